// Round 8
// baseline (638.622 us; speedup 1.0000x reference)
//
#include <hip/hip_runtime.h>
#include <hip/hip_bf16.h>
#include <math.h>

// Problem constants (match reference)
#define RR 10
#define BB 8
#define NN 8192
#define HH 8
#define BN 65536            // BB*NN nodes per ROI
#define EE (1u << 20)       // directed edges per ROI = 2*B*EPAIR
#define EPB (EE / BB)       // 131072 directed edges per (ROI,patient), contiguous
#define NPAIR (EPB / 2)     // 65536 undirected pairs per (r,b)
#define KK 4096             // TopKPooling keeps K of NN
#define NSUP 80             // B*R super nodes

#define NTL(p) __builtin_nontemporal_load(p)

// ---------------- k1: count in-degree per (r,b,dst-quarter); persist per-edge rank (uchar) ----------------
// rank = atomicAdd return = this edge's slot index within its dst's list. 1 atomic/directed edge TOTAL.
__global__ __launch_bounds__(1024)
void count_kernel(const int* __restrict__ ei, unsigned char* __restrict__ rankg,
                  unsigned short* __restrict__ qoffg, int* __restrict__ qtotg) {
  const int bid = blockIdx.x;
  const int rb = bid % 80;
  const int q = bid / 80;                 // dst quarter 0..3
  const int r = rb / BB;
  const int b = rb % BB;
  const int tid = threadIdx.x;

  __shared__ int scnt[2048];
  __shared__ int ps[1024];
  scnt[tid] = 0; scnt[tid + 1024] = 0;
  __syncthreads();

  const int* up = ei + (size_t)r * 2u * EE + (size_t)b * EPB;        // pair u side
  const int* vp = ei + (size_t)r * 2u * EE + EE + (size_t)b * EPB;   // pair v side
  unsigned char* rk = rankg + (size_t)rb * EPB;

  // dir u->v (dst=v) lives at directed index e; dir v->u (dst=u) at e+NPAIR
#define CNT(U, V, E)                                                \
  {                                                                 \
    int lv = (V) & (NN - 1);                                        \
    if ((lv >> 11) == q) {                                          \
      int t0 = atomicAdd(&scnt[lv & 2047], 1);                      \
      rk[E] = (unsigned char)t0;                                    \
    }                                                               \
    int lu = (U) & (NN - 1);                                        \
    if ((lu >> 11) == q) {                                          \
      int t1 = atomicAdd(&scnt[lu & 2047], 1);                      \
      rk[(E) + NPAIR] = (unsigned char)t1;                          \
    }                                                               \
  }
  for (int e0 = tid; e0 + 3072 < NPAIR; e0 += 4096) {
    int u0 = NTL(up + e0);
    int u1 = NTL(up + e0 + 1024);
    int u2 = NTL(up + e0 + 2048);
    int u3 = NTL(up + e0 + 3072);
    int v0 = NTL(vp + e0);
    int v1 = NTL(vp + e0 + 1024);
    int v2 = NTL(vp + e0 + 2048);
    int v3 = NTL(vp + e0 + 3072);
    CNT(u0, v0, e0) CNT(u1, v1, e0 + 1024) CNT(u2, v2, e0 + 2048) CNT(u3, v3, e0 + 3072)
  }
#undef CNT
  __syncthreads();

  // exclusive scan over this quarter's 2048 counts (thread owns 2t, 2t+1)
  int a = scnt[2 * tid], b2 = scnt[2 * tid + 1];
  ps[tid] = a + b2;
  __syncthreads();
  for (int s2 = 1; s2 < 1024; s2 <<= 1) {
    int v = 0;
    if (tid >= s2) v = ps[tid - s2];
    __syncthreads();
    ps[tid] += v;
    __syncthreads();
  }
  int ebase = ps[tid] - a - b2;
  size_t ob = (size_t)rb * 8192 + (size_t)q * 2048;
  qoffg[ob + 2 * tid] = (unsigned short)ebase;         // quarter-local exclusive offsets
  qoffg[ob + 2 * tid + 1] = (unsigned short)(ebase + a);
  if (tid == 1023) qtotg[rb * 4 + q] = ps[1023];       // quarter total
}

// ---------------- k2: scatter (atomic-free, slot = base + qoff + rank) then fused pull ----------------
__global__ __launch_bounds__(1024)
void scatpull_kernel(const int* __restrict__ ei, const float* __restrict__ x,
                     const unsigned char* __restrict__ rankg,
                     const unsigned short* __restrict__ qoffg, const int* __restrict__ qtotg,
                     unsigned short* __restrict__ csrg, float* __restrict__ P4) {
  const int bid = blockIdx.x;
  const int rb = bid % 80;
  const int q = bid / 80;
  const int r = rb / BB;
  const int b = rb % BB;
  const int tid = threadIdx.x;

  __shared__ unsigned short qo[8192];   // 16 KB: all quarters' local offsets
  __shared__ float dls[8192];           // 32 KB: dis for all nodes of (r,b)
  __shared__ int qt4[4];

  for (int i = tid; i < 8192; i += 1024) qo[i] = qoffg[(size_t)rb * 8192 + i];
  if (tid < 4) qt4[tid] = qtotg[rb * 4 + tid];
  __syncthreads();
  for (int i = tid; i < 8192; i += 1024) {
    int idx = i & 2047, qq = i >> 11;
    int nxt = (idx < 2047) ? (int)qo[i + 1] : qt4[qq];
    int c = nxt - (int)qo[i];
    dls[i] = rsqrtf((float)c + 1.0f);
  }
  int baseq = 0;
#pragma unroll
  for (int k = 0; k < 4; ++k) baseq += (k < q) ? qt4[k] : 0;
  __syncthreads();

  const int* up = ei + (size_t)r * 2u * EE + (size_t)b * EPB;
  const int* vp = ei + (size_t)r * 2u * EE + EE + (size_t)b * EPB;
  const unsigned char* rk = rankg + (size_t)rb * EPB;
  unsigned short* csr = csrg + (size_t)rb * EPB;

  // scatter: plain computed writes, zero atomics
#define SCAT(U, V, E)                                               \
  {                                                                 \
    int lv = (V) & (NN - 1);                                        \
    if ((lv >> 11) == q) {                                          \
      int slot = baseq + (int)qo[lv] + (int)rk[E];                  \
      csr[slot] = (unsigned short)((U) & (NN - 1));                 \
    }                                                               \
    int lu = (U) & (NN - 1);                                        \
    if ((lu >> 11) == q) {                                          \
      int slot = baseq + (int)qo[lu] + (int)rk[(E) + NPAIR];        \
      csr[slot] = (unsigned short)((V) & (NN - 1));                 \
    }                                                               \
  }
  for (int e0 = tid; e0 + 3072 < NPAIR; e0 += 4096) {
    int u0 = NTL(up + e0);
    int u1 = NTL(up + e0 + 1024);
    int u2 = NTL(up + e0 + 2048);
    int u3 = NTL(up + e0 + 3072);
    int v0 = NTL(vp + e0);
    int v1 = NTL(vp + e0 + 1024);
    int v2 = NTL(vp + e0 + 2048);
    int v3 = NTL(vp + e0 + 3072);
    SCAT(u0, v0, e0) SCAT(u1, v1, e0 + 1024) SCAT(u2, v2, e0 + 2048) SCAT(u3, v3, e0 + 3072)
  }
#undef SCAT
  __threadfence();
  __syncthreads();   // this block wrote ALL slots of its quarter's nodes -> safe to pull

  // pull: register accumulation, 4-edge ILP. P4[d] = dis[d] * sum dis[s]*x[s]
  const size_t base = (size_t)r * BN + (size_t)b * NN;
  const float4* x4 = (const float4*)x + base;
#pragma unroll
  for (int k = 0; k < 2; ++k) {
    int idx = tid + k * 1024;            // index within quarter
    int n = q * 2048 + idx;              // local node id
    int o = baseq + (int)qo[n];
    int nxt = (idx < 2047) ? (int)qo[n + 1] : qt4[q];
    int c = nxt - (int)qo[n] + ((idx < 2047) ? 0 : 0);
    c = (idx < 2047) ? ((int)qo[n + 1] - (int)qo[n]) : (qt4[q] - (int)qo[n]);
    (void)nxt;
    const unsigned short* lst = csr + o;
    float sx = 0.f, sy = 0.f, sz = 0.f, sw = 0.f;
    int j = 0;
    for (; j + 3 < c; j += 4) {
      int s0 = lst[j], s1 = lst[j + 1], s2 = lst[j + 2], s3 = lst[j + 3];
      float d0 = dls[s0], d1 = dls[s1], d2 = dls[s2], d3 = dls[s3];
      float4 a0 = x4[s0], a1 = x4[s1], a2 = x4[s2], a3 = x4[s3];
      sx += a0.x * d0 + a1.x * d1 + a2.x * d2 + a3.x * d3;
      sy += a0.y * d0 + a1.y * d1 + a2.y * d2 + a3.y * d3;
      sz += a0.z * d0 + a1.z * d1 + a2.z * d2 + a3.z * d3;
      sw += a0.w * d0 + a1.w * d1 + a2.w * d2 + a3.w * d3;
    }
    for (; j < c; ++j) {
      int s0 = lst[j];
      float d0 = dls[s0];
      float4 a0 = x4[s0];
      sx += a0.x * d0; sy += a0.y * d0; sz += a0.z * d0; sw += a0.w * d0;
    }
    float dd = dls[n];
    ((float4*)P4)[base + n] = make_float4(sx * dd, sy * dd, sz * dd, sw * dd);
  }
}

// ---------------- per-(ROI,patient): combine + graph-LN + score + radix-select topK + pools ----------------
__global__ __launch_bounds__(1024)
void roi_kernel(const float* __restrict__ x,
                const float* __restrict__ gcn_w,
                const float* __restrict__ gcn_b,
                const float* __restrict__ ln_w,
                const float* __restrict__ ln_b,
                const float* __restrict__ topk_w,
                const float* __restrict__ cen,
                const unsigned short* __restrict__ qoffg,
                const int* __restrict__ qtotg,
                const float* __restrict__ P4,
                float* __restrict__ feats) {
  const int r = blockIdx.x / BB;
  const int b = blockIdx.x % BB;
  const int rb = blockIdx.x;
  const int tid = threadIdx.x;

  __shared__ unsigned short qos[8192];  // 16 KB
  __shared__ int qt4[4];
  __shared__ double dred[1024];
  __shared__ int tscan[1024];
  __shared__ int hist[256];
  __shared__ float chanSum[8];
  __shared__ float fvSum[8];
  __shared__ int cntGt;
  __shared__ int selb, kleft;

  for (int i = tid; i < 8192; i += 1024) qos[i] = qoffg[(size_t)rb * 8192 + i];
  if (tid < 4) qt4[tid] = qtotg[rb * 4 + tid];
  if (tid < 8) { chanSum[tid] = 0.f; fvSum[tid] = 0.f; }
  if (tid == 0) cntGt = 0;

  float w[32], bg[8], lw[8], lb[8], wt[8];
#pragma unroll
  for (int i = 0; i < 32; ++i) w[i] = gcn_w[r * 32 + i];
  float wn2 = 0.f;
#pragma unroll
  for (int c = 0; c < 8; ++c) {
    bg[c] = gcn_b[r * 8 + c];
    lw[c] = ln_w[r * 8 + c];
    lb[c] = ln_b[r * 8 + c];
    wt[c] = topk_w[r * 8 + c];
    wn2 += wt[c] * wt[c];
  }
  const float invn = 1.0f / sqrtf(wn2);
  __syncthreads();

  const size_t base = (size_t)r * BN + (size_t)b * NN;
  const float4* x4 = (const float4*)x + base;
  const float4* p4 = (const float4*)P4 + base;

  // v4[n] = P4[n] + x[n]/(deg+1) ; hrelu[c] = relu(v4 @ W[:,c] + bg[c])
#define V4(n, out)                                                  \
  {                                                                 \
    int idx_ = (n) & 2047, qq_ = (n) >> 11;                         \
    int nxt_ = (idx_ < 2047) ? (int)qos[(n) + 1] : qt4[qq_];        \
    float invd = 1.0f / ((float)(nxt_ - (int)qos[n]) + 1.0f);       \
    float4 pv = p4[n];                                              \
    float4 xv = x4[n];                                              \
    out.x = pv.x + xv.x * invd;                                     \
    out.y = pv.y + xv.y * invd;                                     \
    out.z = pv.z + xv.z * invd;                                     \
    out.w = pv.w + xv.w * invd;                                     \
  }
#define HREL(v4v, c) fmaxf(v4v.x * w[c] + v4v.y * w[8 + c] + v4v.z * w[16 + c] + v4v.w * w[24 + c] + bg[c], 0.0f)

  // Pass A: fp64 LN stats over hrelu
  double s1 = 0.0, s2 = 0.0;
#pragma unroll
  for (int i = 0; i < 8; ++i) {
    int n = tid * 8 + i;
    float4 vv; V4(n, vv)
#pragma unroll
    for (int c = 0; c < 8; ++c) {
      float v = HREL(vv, c);
      s1 += v;
      s2 += (double)v * v;
    }
  }
  dred[tid] = s1;
  __syncthreads();
  for (int off = 512; off > 0; off >>= 1) {
    if (tid < off) dred[tid] += dred[tid + off];
    __syncthreads();
  }
  double tot1 = dred[0];
  __syncthreads();
  dred[tid] = s2;
  __syncthreads();
  for (int off = 512; off > 0; off >>= 1) {
    if (tid < off) dred[tid] += dred[tid + off];
    __syncthreads();
  }
  double tot2 = dred[0];
  const double M = (double)NN * HH;
  double mu = tot1 / M;
  double var = tot2 / M - mu * mu;
  float muf = (float)mu;
  float rstd = (float)(1.0 / sqrt(var + 1e-5));

  // Pass B: hn, per-channel sums, scores
  float ch[8] = {0, 0, 0, 0, 0, 0, 0, 0};
  float sv[8];
  unsigned fl[8];
#pragma unroll
  for (int i = 0; i < 8; ++i) {
    int n = tid * 8 + i;
    float4 vv; V4(n, vv)
    float pre = 0.f;
#pragma unroll
    for (int c = 0; c < 8; ++c) {
      float v = HREL(vv, c);
      float hn = (v - muf) * rstd * lw[c] + lb[c];
      ch[c] += hn;
      pre += hn * wt[c];
    }
    float s = tanhf(pre * invn);
    sv[i] = s;
    unsigned u = __float_as_uint(s);
    fl[i] = (u & 0x80000000u) ? ~u : (u | 0x80000000u);  // monotonic flip
  }
#pragma unroll
  for (int c = 0; c < 8; ++c) atomicAdd(&chanSum[c], ch[c]);

  // Radix-select the K-th largest (exact), 4 passes of 8 bits
  unsigned prefix = 0;
  int kneed = KK;
  for (int shift = 24; shift >= 0; shift -= 8) {
    __syncthreads();
    if (tid < 256) hist[tid] = 0;
    __syncthreads();
#pragma unroll
    for (int i = 0; i < 8; ++i) {
      bool m = (shift == 24) || ((fl[i] >> (shift + 8)) == prefix);
      if (m) atomicAdd(&hist[(fl[i] >> shift) & 255], 1);
    }
    __syncthreads();
    if (tid == 0) {
      int kn = kneed, bsel = 0;
      for (int bb2 = 255; bb2 >= 0; --bb2) {
        int c = hist[bb2];
        if (kn - c <= 0) { bsel = bb2; break; }
        kn -= c;
      }
      selb = bsel; kleft = kn;
    }
    __syncthreads();
    prefix = (prefix << 8) | (unsigned)selb;
    kneed = kleft;
  }
  float tau = (prefix & 0x80000000u) ? __uint_as_float(prefix & 0x7fffffffu)
                                     : __uint_as_float(~prefix);

  // tie-break lowest-index-first (matches lax.top_k's selected set)
  int cg = 0, ct = 0;
#pragma unroll
  for (int i = 0; i < 8; ++i) {
    if (sv[i] > tau) cg++;
    else if (sv[i] == tau) ct++;
  }
  atomicAdd(&cntGt, cg);
  tscan[tid] = ct;
  __syncthreads();
  if (tid == 0) {
    int run = 0;
    for (int t = 0; t < 1024; ++t) { int tmp = tscan[t]; tscan[t] = run; run += tmp; }
  }
  __syncthreads();
  int quota = KK - cntGt;
  int rank = tscan[tid];
  float fva[8] = {0, 0, 0, 0, 0, 0, 0, 0};
#pragma unroll
  for (int i = 0; i < 8; ++i) {
    bool inc = sv[i] > tau;
    if (!inc && sv[i] == tau) { inc = (rank < quota); rank++; }
    if (inc) {
      int n = tid * 8 + i;
      float4 vv; V4(n, vv)
#pragma unroll
      for (int c = 0; c < 8; ++c) {
        float v = HREL(vv, c);
        float hn = (v - muf) * rstd * lw[c] + lb[c];
        fva[c] += hn * sv[i];
      }
    }
  }
#undef V4
#undef HREL
#pragma unroll
  for (int c = 0; c < 8; ++c) atomicAdd(&fvSum[c], fva[c]);
  __syncthreads();

  size_t fo = (size_t)(r * BB + b) * 19;
  if (tid < 8) {
    feats[fo + tid] = chanSum[tid] / (float)NN;        // res
    feats[fo + 8 + tid] = fvSum[tid] / (float)KK;      // fv
  }
  if (tid >= 16 && tid < 19) {
    feats[fo + tid] = cen[(size_t)(r * BB + b) * 3 + (tid - 16)];
  }
}

// ---------------- super graph: GAT1 -> LN -> GAT2 -> LN -> pool -> linear ----------------
__global__ __launch_bounds__(256)
void super_kernel(const float* __restrict__ feats,
                  const float* __restrict__ W1, const float* __restrict__ as1,
                  const float* __restrict__ ad1, const float* __restrict__ b1,
                  const float* __restrict__ lnw1, const float* __restrict__ lnb1,
                  const float* __restrict__ W2, const float* __restrict__ as2,
                  const float* __restrict__ ad2, const float* __restrict__ b2,
                  const float* __restrict__ lnw2, const float* __restrict__ lnb2,
                  const float* __restrict__ linw, const float* __restrict__ linb,
                  float* __restrict__ out) {
  __shared__ float sx[NSUP * 19];
  __shared__ float h1[NSUP * 64];
  __shared__ float x1[NSUP * 64];
  __shared__ float es1[NSUP * 4], ed1[NSUP * 4];
  __shared__ float h2[NSUP * 16], x2[NSUP * 16];
  __shared__ float es2[NSUP], ed2[NSUP];
  __shared__ float stat[16];
  const int tid = threadIdx.x;

  for (int i = tid; i < NSUP * 19; i += 256) {
    int n = i / 19, c = i % 19;
    int bb = n / RR, rr = n % RR;
    sx[i] = feats[(size_t)(rr * BB + bb) * 19 + c];
  }
  __syncthreads();
  for (int p = tid; p < NSUP * 64; p += 256) {
    int n = p / 64, j = p % 64;
    float acc = 0.f;
    for (int k2 = 0; k2 < 19; ++k2) acc += sx[n * 19 + k2] * W1[k2 * 64 + j];
    h1[p] = acc;
  }
  __syncthreads();
  for (int p = tid; p < NSUP * 4; p += 256) {
    int n = p / 4, hd = p % 4;
    float a = 0.f, d2 = 0.f;
    for (int o = 0; o < 16; ++o) {
      float hv = h1[n * 64 + hd * 16 + o];
      a += hv * as1[hd * 16 + o];
      d2 += hv * ad1[hd * 16 + o];
    }
    es1[p] = a; ed1[p] = d2;
  }
  __syncthreads();
  for (int p = tid; p < NSUP * 64; p += 256) {
    int n = p / 64, j = p % 64, hd = j / 16;
    int rr = n % RR;
    float o;
    if (rr == 0) {
      o = h1[p];
    } else {
      int hub = n - rr;
      float eh = es1[hub * 4 + hd] + ed1[n * 4 + hd];
      float esf = es1[n * 4 + hd] + ed1[n * 4 + hd];
      eh = eh > 0.f ? eh : 0.2f * eh;
      esf = esf > 0.f ? esf : 0.2f * esf;
      float m = fmaxf(eh, esf);
      float wh = expf(eh - m), ws2 = expf(esf - m);
      o = (wh * h1[hub * 64 + j] + ws2 * h1[n * 64 + j]) / (wh + ws2);
    }
    float v = o + b1[j];
    x1[p] = v > 0.f ? v : expm1f(v);   // elu
  }
  __syncthreads();
  if (tid < BB) {
    double m = 0.0, v2 = 0.0;
    for (int q = 0; q < RR * 64; ++q) {
      float val = x1[tid * RR * 64 + q];
      m += val; v2 += (double)val * val;
    }
    m /= (RR * 64.0); v2 = v2 / (RR * 64.0) - m * m;
    stat[tid] = (float)m;
    stat[8 + tid] = (float)(1.0 / sqrt(v2 + 1e-5));
  }
  __syncthreads();
  for (int p = tid; p < NSUP * 64; p += 256) {
    int n = p / 64, j = p % 64, bb = n / RR;
    x1[p] = (x1[p] - stat[bb]) * stat[8 + bb] * lnw1[j] + lnb1[j];
  }
  __syncthreads();
  for (int p = tid; p < NSUP * 16; p += 256) {
    int n = p / 16, o = p % 16;
    float acc = 0.f;
    for (int j = 0; j < 64; ++j) acc += x1[n * 64 + j] * W2[j * 16 + o];
    h2[p] = acc;
  }
  __syncthreads();
  for (int n = tid; n < NSUP; n += 256) {
    float a = 0.f, d2 = 0.f;
    for (int o = 0; o < 16; ++o) {
      float hv = h2[n * 16 + o];
      a += hv * as2[o];
      d2 += hv * ad2[o];
    }
    es2[n] = a; ed2[n] = d2;
  }
  __syncthreads();
  for (int p = tid; p < NSUP * 16; p += 256) {
    int n = p / 16, o = p % 16;
    int rr = n % RR;
    float ov;
    if (rr == 0) ov = h2[p];
    else {
      int hub = n - rr;
      float eh = es2[hub] + ed2[n];
      float esf = es2[n] + ed2[n];
      eh = eh > 0.f ? eh : 0.2f * eh;
      esf = esf > 0.f ? esf : 0.2f * esf;
      float m = fmaxf(eh, esf);
      float wh = expf(eh - m), ws2 = expf(esf - m);
      ov = (wh * h2[hub * 16 + o] + ws2 * h2[p]) / (wh + ws2);
    }
    float v = ov + b2[o];
    x2[p] = v > 0.f ? v : expm1f(v);
  }
  __syncthreads();
  if (tid < BB) {
    double m = 0.0, v2 = 0.0;
    for (int q = 0; q < RR * 16; ++q) {
      float val = x2[tid * RR * 16 + q];
      m += val; v2 += (double)val * val;
    }
    m /= (RR * 16.0); v2 = v2 / (RR * 16.0) - m * m;
    stat[tid] = (float)m;
    stat[8 + tid] = (float)(1.0 / sqrt(v2 + 1e-5));
  }
  __syncthreads();
  for (int p = tid; p < NSUP * 16; p += 256) {
    int n = p / 16, o = p % 16, bb = n / RR;
    x2[p] = (x2[p] - stat[bb]) * stat[8 + bb] * lnw2[o] + lnb2[o];
  }
  __syncthreads();
  if (tid < BB * 2) {
    int bb = tid / 2, t = tid % 2;
    float acc = linb[t];
    for (int o = 0; o < 16; ++o) {
      float pm = 0.f;
      for (int rr = 0; rr < RR; ++rr) pm += x2[(bb * RR + rr) * 16 + o];
      pm /= (float)RR;
      acc += pm * linw[o * 2 + t];
    }
    out[bb * 2 + t] = acc;
  }
}

extern "C" void kernel_launch(void* const* d_in, const int* in_sizes, int n_in,
                              void* d_out, int out_size, void* d_ws, size_t ws_size,
                              hipStream_t stream) {
  const float* roi_x = (const float*)d_in[0];
  const int* ei = (const int*)d_in[1];
  const float* cen = (const float*)d_in[2];
  const float* gcn_w = (const float*)d_in[3];
  const float* gcn_b = (const float*)d_in[4];
  const float* ln_w = (const float*)d_in[5];
  const float* ln_b = (const float*)d_in[6];
  const float* topk_w = (const float*)d_in[7];
  const float* gat1_w = (const float*)d_in[8];
  const float* as1 = (const float*)d_in[9];
  const float* ad1 = (const float*)d_in[10];
  const float* b1 = (const float*)d_in[11];
  const float* lnw1 = (const float*)d_in[12];
  const float* lnb1 = (const float*)d_in[13];
  const float* W2 = (const float*)d_in[14];
  const float* as2 = (const float*)d_in[15];
  const float* ad2 = (const float*)d_in[16];
  const float* b2 = (const float*)d_in[17];
  const float* lnw2 = (const float*)d_in[18];
  const float* lnb2 = (const float*)d_in[19];
  const float* linw = (const float*)d_in[20];
  const float* linb = (const float*)d_in[21];
  float* out = (float*)d_out;

  // ws layout (bytes): P4 f32 [R*BN*4] =10.49MB | csr u16 [80*EPB] =20.97MB
  //  | qoff u16 [80*8192] =1.31MB | qtot i32 [320] | feats f32 [1520] | rank u8 [80*EPB] =10.49MB
  //  total 43.26MB  (<= 44.57MB proven available in R5)
  char* wsb = (char*)d_ws;
  float* P4 = (float*)wsb;
  unsigned short* csr = (unsigned short*)(wsb + (size_t)RR * BN * 4 * 4);
  unsigned short* qoff = csr + (size_t)80 * EPB;
  int* qtot = (int*)((char*)qoff + (size_t)80 * 8192 * 2);
  float* feats = (float*)((char*)qtot + 320 * 4);
  unsigned char* rankg = (unsigned char*)((char*)feats + (size_t)RR * BB * 19 * 4);

  count_kernel<<<320, 1024, 0, stream>>>(ei, rankg, qoff, qtot);
  scatpull_kernel<<<320, 1024, 0, stream>>>(ei, roi_x, rankg, qoff, qtot, csr, P4);
  roi_kernel<<<RR * BB, 1024, 0, stream>>>(roi_x, gcn_w, gcn_b, ln_w, ln_b,
                                           topk_w, cen, qoff, qtot, P4, feats);
  super_kernel<<<1, 256, 0, stream>>>(feats, gat1_w, as1, ad1, b1, lnw1, lnb1,
                                      W2, as2, ad2, b2, lnw2, lnb2, linw, linb, out);
}

// Round 10
// 443.863 us; speedup vs baseline: 1.4388x; 1.4388x over previous
//
#include <hip/hip_runtime.h>
#include <hip/hip_bf16.h>
#include <math.h>

// Problem constants (match reference)
#define RR 10
#define BB 8
#define NN 8192
#define HH 8
#define BN 65536            // BB*NN nodes per ROI
#define EE (1u << 20)       // directed edges per ROI = 2*B*EPAIR
#define EPB (EE / BB)       // 131072 directed edges per (ROI,patient), contiguous
#define NPAIR (EPB / 2)     // 65536 undirected pairs per (r,b)
#define KK 4096             // TopKPooling keeps K of NN
#define NSUP 80             // B*R super nodes

#define NTL(p) __builtin_nontemporal_load(p)

// ---------------- k1: count in-degree per (r,b,dst-quarter); persist per-edge rank (uchar) ----------------
// rank = atomicAdd return = this edge's slot index within its dst's list. 1 atomic/directed edge TOTAL.
__global__ __launch_bounds__(1024)
void count_kernel(const int* __restrict__ ei, unsigned char* __restrict__ rankg,
                  unsigned short* __restrict__ qoffg, int* __restrict__ qtotg) {
  const int bid = blockIdx.x;
  const int rb = bid % 80;
  const int q = bid / 80;                 // dst quarter 0..3
  const int r = rb / BB;
  const int b = rb % BB;
  const int tid = threadIdx.x;

  __shared__ int scnt[2048];
  __shared__ int ps[1024];
  scnt[tid] = 0; scnt[tid + 1024] = 0;
  __syncthreads();

  const int* up = ei + (size_t)r * 2u * EE + (size_t)b * EPB;        // pair u side
  const int* vp = ei + (size_t)r * 2u * EE + EE + (size_t)b * EPB;   // pair v side
  unsigned char* rk = rankg + (size_t)rb * EPB;

  // dir u->v (dst=v) lives at directed index e; dir v->u (dst=u) at e+NPAIR
#define CNT(U, V, E)                                                \
  {                                                                 \
    int lv = (V) & (NN - 1);                                        \
    if ((lv >> 11) == q) {                                          \
      int t0 = atomicAdd(&scnt[lv & 2047], 1);                      \
      rk[E] = (unsigned char)t0;                                    \
    }                                                               \
    int lu = (U) & (NN - 1);                                        \
    if ((lu >> 11) == q) {                                          \
      int t1 = atomicAdd(&scnt[lu & 2047], 1);                      \
      rk[(E) + NPAIR] = (unsigned char)t1;                          \
    }                                                               \
  }
  for (int e0 = tid; e0 + 3072 < NPAIR; e0 += 4096) {
    int u0 = NTL(up + e0);
    int u1 = NTL(up + e0 + 1024);
    int u2 = NTL(up + e0 + 2048);
    int u3 = NTL(up + e0 + 3072);
    int v0 = NTL(vp + e0);
    int v1 = NTL(vp + e0 + 1024);
    int v2 = NTL(vp + e0 + 2048);
    int v3 = NTL(vp + e0 + 3072);
    CNT(u0, v0, e0) CNT(u1, v1, e0 + 1024) CNT(u2, v2, e0 + 2048) CNT(u3, v3, e0 + 3072)
  }
#undef CNT
  __syncthreads();

  // exclusive scan over this quarter's 2048 counts (thread owns 2t, 2t+1)
  int a = scnt[2 * tid], b2 = scnt[2 * tid + 1];
  ps[tid] = a + b2;
  __syncthreads();
  for (int s2 = 1; s2 < 1024; s2 <<= 1) {
    int v = 0;
    if (tid >= s2) v = ps[tid - s2];
    __syncthreads();
    ps[tid] += v;
    __syncthreads();
  }
  int ebase = ps[tid] - a - b2;
  size_t ob = (size_t)rb * 8192 + (size_t)q * 2048;
  qoffg[ob + 2 * tid] = (unsigned short)ebase;         // quarter-local exclusive offsets
  qoffg[ob + 2 * tid + 1] = (unsigned short)(ebase + a);
  if (tid == 1023) qtotg[rb * 4 + q] = ps[1023];       // quarter total
}

// ---------------- k2: scatter (atomic-free, slot = base + qoff + rank) then fused pull ----------------
// NOTE: no __threadfence needed -- each block reads back ONLY csr slots it wrote itself;
// __syncthreads() provides workgroup-scope global visibility. (R8's device-scope fence
// forced per-wave XCD-L2 writebacks: 300MB WRITE_SIZE, 455us.)
__global__ __launch_bounds__(1024)
void scatpull_kernel(const int* __restrict__ ei, const float* __restrict__ x,
                     const unsigned char* __restrict__ rankg,
                     const unsigned short* __restrict__ qoffg, const int* __restrict__ qtotg,
                     unsigned short* __restrict__ csrg, float* __restrict__ P4) {
  const int bid = blockIdx.x;
  const int rb = bid % 80;
  const int q = bid / 80;
  const int r = rb / BB;
  const int b = rb % BB;
  const int tid = threadIdx.x;

  __shared__ unsigned short qo[8192];   // 16 KB: all quarters' local offsets
  __shared__ float dls[8192];           // 32 KB: dis for all nodes of (r,b)
  __shared__ int qt4[4];

  for (int i = tid; i < 8192; i += 1024) qo[i] = qoffg[(size_t)rb * 8192 + i];
  if (tid < 4) qt4[tid] = qtotg[rb * 4 + tid];
  __syncthreads();
  for (int i = tid; i < 8192; i += 1024) {
    int idx = i & 2047, qq = i >> 11;
    int nxt = (idx < 2047) ? (int)qo[i + 1] : qt4[qq];
    int c = nxt - (int)qo[i];
    dls[i] = rsqrtf((float)c + 1.0f);
  }
  int baseq = 0;
#pragma unroll
  for (int k = 0; k < 4; ++k) baseq += (k < q) ? qt4[k] : 0;
  __syncthreads();

  const int* up = ei + (size_t)r * 2u * EE + (size_t)b * EPB;
  const int* vp = ei + (size_t)r * 2u * EE + EE + (size_t)b * EPB;
  const unsigned char* rk = rankg + (size_t)rb * EPB;
  unsigned short* csr = csrg + (size_t)rb * EPB;

  // scatter: plain computed writes, zero atomics
#define SCAT(U, V, E)                                               \
  {                                                                 \
    int lv = (V) & (NN - 1);                                        \
    if ((lv >> 11) == q) {                                          \
      int slot = baseq + (int)qo[lv] + (int)rk[E];                  \
      csr[slot] = (unsigned short)((U) & (NN - 1));                 \
    }                                                               \
    int lu = (U) & (NN - 1);                                        \
    if ((lu >> 11) == q) {                                          \
      int slot = baseq + (int)qo[lu] + (int)rk[(E) + NPAIR];        \
      csr[slot] = (unsigned short)((V) & (NN - 1));                 \
    }                                                               \
  }
  for (int e0 = tid; e0 + 3072 < NPAIR; e0 += 4096) {
    int u0 = NTL(up + e0);
    int u1 = NTL(up + e0 + 1024);
    int u2 = NTL(up + e0 + 2048);
    int u3 = NTL(up + e0 + 3072);
    int v0 = NTL(vp + e0);
    int v1 = NTL(vp + e0 + 1024);
    int v2 = NTL(vp + e0 + 2048);
    int v3 = NTL(vp + e0 + 3072);
    SCAT(u0, v0, e0) SCAT(u1, v1, e0 + 1024) SCAT(u2, v2, e0 + 2048) SCAT(u3, v3, e0 + 3072)
  }
#undef SCAT
  __syncthreads();   // block-scope visibility: this block wrote ALL slots of its quarter

  // pull: register accumulation, 4-edge ILP. P4[d] = dis[d] * sum dis[s]*x[s]
  const size_t base = (size_t)r * BN + (size_t)b * NN;
  const float4* x4 = (const float4*)x + base;
#pragma unroll
  for (int k = 0; k < 2; ++k) {
    int idx = tid + k * 1024;            // index within quarter
    int n = q * 2048 + idx;              // local node id
    int o = baseq + (int)qo[n];
    int c = (idx < 2047) ? ((int)qo[n + 1] - (int)qo[n]) : (qt4[q] - (int)qo[n]);
    const unsigned short* lst = csr + o;
    float sx = 0.f, sy = 0.f, sz = 0.f, sw = 0.f;
    int j = 0;
    for (; j + 3 < c; j += 4) {
      int s0 = lst[j], s1 = lst[j + 1], s2 = lst[j + 2], s3 = lst[j + 3];
      float d0 = dls[s0], d1 = dls[s1], d2 = dls[s2], d3 = dls[s3];
      float4 a0 = x4[s0], a1 = x4[s1], a2 = x4[s2], a3 = x4[s3];
      sx += a0.x * d0 + a1.x * d1 + a2.x * d2 + a3.x * d3;
      sy += a0.y * d0 + a1.y * d1 + a2.y * d2 + a3.y * d3;
      sz += a0.z * d0 + a1.z * d1 + a2.z * d2 + a3.z * d3;
      sw += a0.w * d0 + a1.w * d1 + a2.w * d2 + a3.w * d3;
    }
    for (; j < c; ++j) {
      int s0 = lst[j];
      float d0 = dls[s0];
      float4 a0 = x4[s0];
      sx += a0.x * d0; sy += a0.y * d0; sz += a0.z * d0; sw += a0.w * d0;
    }
    float dd = dls[n];
    ((float4*)P4)[base + n] = make_float4(sx * dd, sy * dd, sz * dd, sw * dd);
  }
}

// ---------------- per-(ROI,patient): combine + graph-LN + score + radix-select topK + pools ----------------
__global__ __launch_bounds__(1024)
void roi_kernel(const float* __restrict__ x,
                const float* __restrict__ gcn_w,
                const float* __restrict__ gcn_b,
                const float* __restrict__ ln_w,
                const float* __restrict__ ln_b,
                const float* __restrict__ topk_w,
                const float* __restrict__ cen,
                const unsigned short* __restrict__ qoffg,
                const int* __restrict__ qtotg,
                const float* __restrict__ P4,
                float* __restrict__ feats) {
  const int r = blockIdx.x / BB;
  const int b = blockIdx.x % BB;
  const int rb = blockIdx.x;
  const int tid = threadIdx.x;

  __shared__ unsigned short qos[8192];  // 16 KB
  __shared__ int qt4[4];
  __shared__ double dred[1024];
  __shared__ int tscan[1024];
  __shared__ int hist[256];
  __shared__ float chanSum[8];
  __shared__ float fvSum[8];
  __shared__ int cntGt;
  __shared__ int selb, kleft;

  for (int i = tid; i < 8192; i += 1024) qos[i] = qoffg[(size_t)rb * 8192 + i];
  if (tid < 4) qt4[tid] = qtotg[rb * 4 + tid];
  if (tid < 8) { chanSum[tid] = 0.f; fvSum[tid] = 0.f; }
  if (tid == 0) cntGt = 0;

  float w[32], bg[8], lw[8], lb[8], wt[8];
#pragma unroll
  for (int i = 0; i < 32; ++i) w[i] = gcn_w[r * 32 + i];
  float wn2 = 0.f;
#pragma unroll
  for (int c = 0; c < 8; ++c) {
    bg[c] = gcn_b[r * 8 + c];
    lw[c] = ln_w[r * 8 + c];
    lb[c] = ln_b[r * 8 + c];
    wt[c] = topk_w[r * 8 + c];
    wn2 += wt[c] * wt[c];
  }
  const float invn = 1.0f / sqrtf(wn2);
  __syncthreads();

  const size_t base = (size_t)r * BN + (size_t)b * NN;
  const float4* x4 = (const float4*)x + base;
  const float4* p4 = (const float4*)P4 + base;

  // v4[n] = P4[n] + x[n]/(deg+1) ; hrelu[c] = relu(v4 @ W[:,c] + bg[c])
#define V4(n, out)                                                  \
  {                                                                 \
    int idx_ = (n) & 2047, qq_ = (n) >> 11;                         \
    int nxt_ = (idx_ < 2047) ? (int)qos[(n) + 1] : qt4[qq_];        \
    float invd = 1.0f / ((float)(nxt_ - (int)qos[n]) + 1.0f);       \
    float4 pv = p4[n];                                              \
    float4 xv = x4[n];                                              \
    out.x = pv.x + xv.x * invd;                                     \
    out.y = pv.y + xv.y * invd;                                     \
    out.z = pv.z + xv.z * invd;                                     \
    out.w = pv.w + xv.w * invd;                                     \
  }
#define HREL(v4v, c) fmaxf(v4v.x * w[c] + v4v.y * w[8 + c] + v4v.z * w[16 + c] + v4v.w * w[24 + c] + bg[c], 0.0f)

  // Pass A: fp64 LN stats over hrelu
  double s1 = 0.0, s2 = 0.0;
#pragma unroll
  for (int i = 0; i < 8; ++i) {
    int n = tid * 8 + i;
    float4 vv; V4(n, vv)
#pragma unroll
    for (int c = 0; c < 8; ++c) {
      float v = HREL(vv, c);
      s1 += v;
      s2 += (double)v * v;
    }
  }
  dred[tid] = s1;
  __syncthreads();
  for (int off = 512; off > 0; off >>= 1) {
    if (tid < off) dred[tid] += dred[tid + off];
    __syncthreads();
  }
  double tot1 = dred[0];
  __syncthreads();
  dred[tid] = s2;
  __syncthreads();
  for (int off = 512; off > 0; off >>= 1) {
    if (tid < off) dred[tid] += dred[tid + off];
    __syncthreads();
  }
  double tot2 = dred[0];
  const double M = (double)NN * HH;
  double mu = tot1 / M;
  double var = tot2 / M - mu * mu;
  float muf = (float)mu;
  float rstd = (float)(1.0 / sqrt(var + 1e-5));

  // Pass B: hn, per-channel sums, scores
  float ch[8] = {0, 0, 0, 0, 0, 0, 0, 0};
  float sv[8];
  unsigned fl[8];
#pragma unroll
  for (int i = 0; i < 8; ++i) {
    int n = tid * 8 + i;
    float4 vv; V4(n, vv)
    float pre = 0.f;
#pragma unroll
    for (int c = 0; c < 8; ++c) {
      float v = HREL(vv, c);
      float hn = (v - muf) * rstd * lw[c] + lb[c];
      ch[c] += hn;
      pre += hn * wt[c];
    }
    float s = tanhf(pre * invn);
    sv[i] = s;
    unsigned u = __float_as_uint(s);
    fl[i] = (u & 0x80000000u) ? ~u : (u | 0x80000000u);  // monotonic flip
  }
#pragma unroll
  for (int c = 0; c < 8; ++c) atomicAdd(&chanSum[c], ch[c]);

  // Radix-select the K-th largest (exact), 4 passes of 8 bits
  unsigned prefix = 0;
  int kneed = KK;
  for (int shift = 24; shift >= 0; shift -= 8) {
    __syncthreads();
    if (tid < 256) hist[tid] = 0;
    __syncthreads();
#pragma unroll
    for (int i = 0; i < 8; ++i) {
      bool m = (shift == 24) || ((fl[i] >> (shift + 8)) == prefix);
      if (m) atomicAdd(&hist[(fl[i] >> shift) & 255], 1);
    }
    __syncthreads();
    if (tid == 0) {
      int kn = kneed, bsel = 0;
      for (int bb2 = 255; bb2 >= 0; --bb2) {
        int c = hist[bb2];
        if (kn - c <= 0) { bsel = bb2; break; }
        kn -= c;
      }
      selb = bsel; kleft = kn;
    }
    __syncthreads();
    prefix = (prefix << 8) | (unsigned)selb;
    kneed = kleft;
  }
  float tau = (prefix & 0x80000000u) ? __uint_as_float(prefix & 0x7fffffffu)
                                     : __uint_as_float(~prefix);

  // tie-break lowest-index-first (matches lax.top_k's selected set)
  int cg = 0, ct = 0;
#pragma unroll
  for (int i = 0; i < 8; ++i) {
    if (sv[i] > tau) cg++;
    else if (sv[i] == tau) ct++;
  }
  atomicAdd(&cntGt, cg);
  tscan[tid] = ct;
  __syncthreads();
  if (tid == 0) {
    int run = 0;
    for (int t = 0; t < 1024; ++t) { int tmp = tscan[t]; tscan[t] = run; run += tmp; }
  }
  __syncthreads();
  int quota = KK - cntGt;
  int rank = tscan[tid];
  float fva[8] = {0, 0, 0, 0, 0, 0, 0, 0};
#pragma unroll
  for (int i = 0; i < 8; ++i) {
    bool inc = sv[i] > tau;
    if (!inc && sv[i] == tau) { inc = (rank < quota); rank++; }
    if (inc) {
      int n = tid * 8 + i;
      float4 vv; V4(n, vv)
#pragma unroll
      for (int c = 0; c < 8; ++c) {
        float v = HREL(vv, c);
        float hn = (v - muf) * rstd * lw[c] + lb[c];
        fva[c] += hn * sv[i];
      }
    }
  }
#undef V4
#undef HREL
#pragma unroll
  for (int c = 0; c < 8; ++c) atomicAdd(&fvSum[c], fva[c]);
  __syncthreads();

  size_t fo = (size_t)(r * BB + b) * 19;
  if (tid < 8) {
    feats[fo + tid] = chanSum[tid] / (float)NN;        // res
    feats[fo + 8 + tid] = fvSum[tid] / (float)KK;      // fv
  }
  if (tid >= 16 && tid < 19) {
    feats[fo + tid] = cen[(size_t)(r * BB + b) * 3 + (tid - 16)];
  }
}

// ---------------- super graph: GAT1 -> LN -> GAT2 -> LN -> pool -> linear ----------------
__global__ __launch_bounds__(256)
void super_kernel(const float* __restrict__ feats,
                  const float* __restrict__ W1, const float* __restrict__ as1,
                  const float* __restrict__ ad1, const float* __restrict__ b1,
                  const float* __restrict__ lnw1, const float* __restrict__ lnb1,
                  const float* __restrict__ W2, const float* __restrict__ as2,
                  const float* __restrict__ ad2, const float* __restrict__ b2,
                  const float* __restrict__ lnw2, const float* __restrict__ lnb2,
                  const float* __restrict__ linw, const float* __restrict__ linb,
                  float* __restrict__ out) {
  __shared__ float sx[NSUP * 19];
  __shared__ float h1[NSUP * 64];
  __shared__ float x1[NSUP * 64];
  __shared__ float es1[NSUP * 4], ed1[NSUP * 4];
  __shared__ float h2[NSUP * 16], x2[NSUP * 16];
  __shared__ float es2[NSUP], ed2[NSUP];
  __shared__ float stat[16];
  const int tid = threadIdx.x;

  for (int i = tid; i < NSUP * 19; i += 256) {
    int n = i / 19, c = i % 19;
    int bb = n / RR, rr = n % RR;
    sx[i] = feats[(size_t)(rr * BB + bb) * 19 + c];
  }
  __syncthreads();
  for (int p = tid; p < NSUP * 64; p += 256) {
    int n = p / 64, j = p % 64;
    float acc = 0.f;
    for (int k2 = 0; k2 < 19; ++k2) acc += sx[n * 19 + k2] * W1[k2 * 64 + j];
    h1[p] = acc;
  }
  __syncthreads();
  for (int p = tid; p < NSUP * 4; p += 256) {
    int n = p / 4, hd = p % 4;
    float a = 0.f, d2 = 0.f;
    for (int o = 0; o < 16; ++o) {
      float hv = h1[n * 64 + hd * 16 + o];
      a += hv * as1[hd * 16 + o];
      d2 += hv * ad1[hd * 16 + o];
    }
    es1[p] = a; ed1[p] = d2;
  }
  __syncthreads();
  for (int p = tid; p < NSUP * 64; p += 256) {
    int n = p / 64, j = p % 64, hd = j / 16;
    int rr = n % RR;
    float o;
    if (rr == 0) {
      o = h1[p];
    } else {
      int hub = n - rr;
      float eh = es1[hub * 4 + hd] + ed1[n * 4 + hd];
      float esf = es1[n * 4 + hd] + ed1[n * 4 + hd];
      eh = eh > 0.f ? eh : 0.2f * eh;
      esf = esf > 0.f ? esf : 0.2f * esf;
      float m = fmaxf(eh, esf);
      float wh = expf(eh - m), ws2 = expf(esf - m);
      o = (wh * h1[hub * 64 + j] + ws2 * h1[n * 64 + j]) / (wh + ws2);
    }
    float v = o + b1[j];
    x1[p] = v > 0.f ? v : expm1f(v);   // elu
  }
  __syncthreads();
  if (tid < BB) {
    double m = 0.0, v2 = 0.0;
    for (int q = 0; q < RR * 64; ++q) {
      float val = x1[tid * RR * 64 + q];
      m += val; v2 += (double)val * val;
    }
    m /= (RR * 64.0); v2 = v2 / (RR * 64.0) - m * m;
    stat[tid] = (float)m;
    stat[8 + tid] = (float)(1.0 / sqrt(v2 + 1e-5));
  }
  __syncthreads();
  for (int p = tid; p < NSUP * 64; p += 256) {
    int n = p / 64, j = p % 64, bb = n / RR;
    x1[p] = (x1[p] - stat[bb]) * stat[8 + bb] * lnw1[j] + lnb1[j];
  }
  __syncthreads();
  for (int p = tid; p < NSUP * 16; p += 256) {
    int n = p / 16, o = p % 16;
    float acc = 0.f;
    for (int j = 0; j < 64; ++j) acc += x1[n * 64 + j] * W2[j * 16 + o];
    h2[p] = acc;
  }
  __syncthreads();
  for (int n = tid; n < NSUP; n += 256) {
    float a = 0.f, d2 = 0.f;
    for (int o = 0; o < 16; ++o) {
      float hv = h2[n * 16 + o];
      a += hv * as2[o];
      d2 += hv * ad2[o];
    }
    es2[n] = a; ed2[n] = d2;
  }
  __syncthreads();
  for (int p = tid; p < NSUP * 16; p += 256) {
    int n = p / 16, o = p % 16;
    int rr = n % RR;
    float ov;
    if (rr == 0) ov = h2[p];
    else {
      int hub = n - rr;
      float eh = es2[hub] + ed2[n];
      float esf = es2[n] + ed2[n];
      eh = eh > 0.f ? eh : 0.2f * eh;
      esf = esf > 0.f ? esf : 0.2f * esf;
      float m = fmaxf(eh, esf);
      float wh = expf(eh - m), ws2 = expf(esf - m);
      ov = (wh * h2[hub * 16 + o] + ws2 * h2[p]) / (wh + ws2);
    }
    float v = ov + b2[o];
    x2[p] = v > 0.f ? v : expm1f(v);
  }
  __syncthreads();
  if (tid < BB) {
    double m = 0.0, v2 = 0.0;
    for (int q = 0; q < RR * 16; ++q) {
      float val = x2[tid * RR * 16 + q];
      m += val; v2 += (double)val * val;
    }
    m /= (RR * 16.0); v2 = v2 / (RR * 16.0) - m * m;
    stat[tid] = (float)m;
    stat[8 + tid] = (float)(1.0 / sqrt(v2 + 1e-5));
  }
  __syncthreads();
  for (int p = tid; p < NSUP * 16; p += 256) {
    int n = p / 16, o = p % 16, bb = n / RR;
    x2[p] = (x2[p] - stat[bb]) * stat[8 + bb] * lnw2[o] + lnb2[o];
  }
  __syncthreads();
  if (tid < BB * 2) {
    int bb = tid / 2, t = tid % 2;
    float acc = linb[t];
    for (int o = 0; o < 16; ++o) {
      float pm = 0.f;
      for (int rr = 0; rr < RR; ++rr) pm += x2[(bb * RR + rr) * 16 + o];
      pm /= (float)RR;
      acc += pm * linw[o * 2 + t];
    }
    out[bb * 2 + t] = acc;
  }
}

extern "C" void kernel_launch(void* const* d_in, const int* in_sizes, int n_in,
                              void* d_out, int out_size, void* d_ws, size_t ws_size,
                              hipStream_t stream) {
  const float* roi_x = (const float*)d_in[0];
  const int* ei = (const int*)d_in[1];
  const float* cen = (const float*)d_in[2];
  const float* gcn_w = (const float*)d_in[3];
  const float* gcn_b = (const float*)d_in[4];
  const float* ln_w = (const float*)d_in[5];
  const float* ln_b = (const float*)d_in[6];
  const float* topk_w = (const float*)d_in[7];
  const float* gat1_w = (const float*)d_in[8];
  const float* as1 = (const float*)d_in[9];
  const float* ad1 = (const float*)d_in[10];
  const float* b1 = (const float*)d_in[11];
  const float* lnw1 = (const float*)d_in[12];
  const float* lnb1 = (const float*)d_in[13];
  const float* W2 = (const float*)d_in[14];
  const float* as2 = (const float*)d_in[15];
  const float* ad2 = (const float*)d_in[16];
  const float* b2 = (const float*)d_in[17];
  const float* lnw2 = (const float*)d_in[18];
  const float* lnb2 = (const float*)d_in[19];
  const float* linw = (const float*)d_in[20];
  const float* linb = (const float*)d_in[21];
  float* out = (float*)d_out;

  // ws layout (bytes): P4 f32 [R*BN*4] =10.49MB | csr u16 [80*EPB] =20.97MB
  //  | qoff u16 [80*8192] =1.31MB | qtot i32 [320] | feats f32 [1520] | rank u8 [80*EPB] =10.49MB
  //  total 43.26MB  (<= 44.57MB proven available in R5)
  char* wsb = (char*)d_ws;
  float* P4 = (float*)wsb;
  unsigned short* csr = (unsigned short*)(wsb + (size_t)RR * BN * 4 * 4);
  unsigned short* qoff = csr + (size_t)80 * EPB;
  int* qtot = (int*)((char*)qoff + (size_t)80 * 8192 * 2);
  float* feats = (float*)((char*)qtot + 320 * 4);
  unsigned char* rankg = (unsigned char*)((char*)feats + (size_t)RR * BB * 19 * 4);

  count_kernel<<<320, 1024, 0, stream>>>(ei, rankg, qoff, qtot);
  scatpull_kernel<<<320, 1024, 0, stream>>>(ei, roi_x, rankg, qoff, qtot, csr, P4);
  roi_kernel<<<RR * BB, 1024, 0, stream>>>(roi_x, gcn_w, gcn_b, ln_w, ln_b,
                                           topk_w, cen, qoff, qtot, P4, feats);
  super_kernel<<<1, 256, 0, stream>>>(feats, gat1_w, as1, ad1, b1, lnw1, lnb1,
                                      W2, as2, ad2, b2, lnw2, lnb2, linw, linb, out);
}

// Round 11
// 308.275 us; speedup vs baseline: 2.0716x; 1.4398x over previous
//
#include <hip/hip_runtime.h>
#include <hip/hip_bf16.h>
#include <math.h>

// Problem constants (match reference)
#define RR 10
#define BB 8
#define NN 8192
#define HH 8
#define BN 65536            // BB*NN nodes per ROI
#define EE (1u << 20)       // directed edges per ROI = 2*B*EPAIR
#define EPB (EE / BB)       // 131072 directed edges per (ROI,patient), contiguous
#define NPAIR (EPB / 2)     // 65536 undirected pairs per (r,b)
#define KK 4096             // TopKPooling keeps K of NN
#define NSUP 80             // B*R super nodes
#define CSRL 34560          // LDS CSR slots per quarter: mean 32768, sigma~157 -> +11 sigma

#define NTL(p) __builtin_nontemporal_load(p)

// ---------------- k1: count in-degree per (r,b,dst-quarter); persist per-edge rank (uchar) ----------------
// rank = atomicAdd return = this edge's slot index within its dst's list. 1 atomic/directed edge TOTAL.
__global__ __launch_bounds__(1024)
void count_kernel(const int* __restrict__ ei, unsigned char* __restrict__ rankg,
                  unsigned short* __restrict__ qoffg, int* __restrict__ qtotg) {
  const int bid = blockIdx.x;
  const int rb = bid % 80;
  const int q = bid / 80;                 // dst quarter 0..3
  const int r = rb / BB;
  const int b = rb % BB;
  const int tid = threadIdx.x;

  __shared__ int scnt[2048];
  __shared__ int ps[1024];
  scnt[tid] = 0; scnt[tid + 1024] = 0;
  __syncthreads();

  const int* up = ei + (size_t)r * 2u * EE + (size_t)b * EPB;        // pair u side
  const int* vp = ei + (size_t)r * 2u * EE + EE + (size_t)b * EPB;   // pair v side
  unsigned char* rk = rankg + (size_t)rb * EPB;

  // dir u->v (dst=v) lives at directed index e; dir v->u (dst=u) at e+NPAIR
#define CNT(U, V, E)                                                \
  {                                                                 \
    int lv = (V) & (NN - 1);                                        \
    if ((lv >> 11) == q) {                                          \
      int t0 = atomicAdd(&scnt[lv & 2047], 1);                      \
      rk[E] = (unsigned char)t0;                                    \
    }                                                               \
    int lu = (U) & (NN - 1);                                        \
    if ((lu >> 11) == q) {                                          \
      int t1 = atomicAdd(&scnt[lu & 2047], 1);                      \
      rk[(E) + NPAIR] = (unsigned char)t1;                          \
    }                                                               \
  }
  for (int e0 = tid; e0 + 3072 < NPAIR; e0 += 4096) {
    int u0 = NTL(up + e0);
    int u1 = NTL(up + e0 + 1024);
    int u2 = NTL(up + e0 + 2048);
    int u3 = NTL(up + e0 + 3072);
    int v0 = NTL(vp + e0);
    int v1 = NTL(vp + e0 + 1024);
    int v2 = NTL(vp + e0 + 2048);
    int v3 = NTL(vp + e0 + 3072);
    CNT(u0, v0, e0) CNT(u1, v1, e0 + 1024) CNT(u2, v2, e0 + 2048) CNT(u3, v3, e0 + 3072)
  }
#undef CNT
  __syncthreads();

  // exclusive scan over this quarter's 2048 counts (thread owns 2t, 2t+1)
  int a = scnt[2 * tid], b2 = scnt[2 * tid + 1];
  ps[tid] = a + b2;
  __syncthreads();
  for (int s2 = 1; s2 < 1024; s2 <<= 1) {
    int v = 0;
    if (tid >= s2) v = ps[tid - s2];
    __syncthreads();
    ps[tid] += v;
    __syncthreads();
  }
  int ebase = ps[tid] - a - b2;
  size_t ob = (size_t)rb * 8192 + (size_t)q * 2048;
  qoffg[ob + 2 * tid] = (unsigned short)ebase;         // quarter-local exclusive offsets
  qoffg[ob + 2 * tid + 1] = (unsigned short)(ebase + a);
  if (tid == 1023) qtotg[rb * 4 + q] = ps[1023];       // quarter total
}

// ---------------- k2: scatter into LDS CSR (atomic-free) then fused pull ----------------
// CSR never leaves the CU: R10 showed global 2B-scattered csr stores caused ~280MB of
// XCD-L2 writeback thrash (write+readback). Quarter CSR fits in 69KB LDS.
// P4[d] = dis[d] * sum_{s in N(d)} dis[s] * x[s]
__global__ __launch_bounds__(1024)
void scatpull_kernel(const int* __restrict__ ei, const float* __restrict__ x,
                     const unsigned char* __restrict__ rankg,
                     const unsigned short* __restrict__ qoffg, const int* __restrict__ qtotg,
                     float* __restrict__ P4) {
  const int bid = blockIdx.x;
  const int rb = bid % 80;
  const int q = bid / 80;
  const int r = rb / BB;
  const int b = rb % BB;
  const int tid = threadIdx.x;

  __shared__ unsigned short qoq[2048];     // own-quarter exclusive offsets (4 KB)
  __shared__ unsigned char degL[NN];       // degree of ALL nodes of (r,b) (8 KB)
  __shared__ unsigned short csrL[CSRL];    // own-quarter CSR src ids (67.5 KB)  -> total 81.4KB, 2 blk/CU
  __shared__ int qt4[4];

  if (tid < 4) qt4[tid] = qtotg[rb * 4 + tid];
  __syncthreads();
  const unsigned short* qof = qoffg + (size_t)rb * 8192;
  for (int i = tid; i < NN; i += 1024) {
    int idx = i & 2047, qq = i >> 11;
    int cur = qof[i];
    int nxt = (idx < 2047) ? (int)qof[i + 1] : qt4[qq];
    degL[i] = (unsigned char)(nxt - cur);
    if (qq == q) qoq[idx] = (unsigned short)cur;
  }
  __syncthreads();

  const int* up = ei + (size_t)r * 2u * EE + (size_t)b * EPB;
  const int* vp = ei + (size_t)r * 2u * EE + EE + (size_t)b * EPB;
  const unsigned char* rk = rankg + (size_t)rb * EPB;

  // scatter: plain LDS stores, race-free by precomputed rank
#define SCAT(U, V, E)                                               \
  {                                                                 \
    int lv = (V) & (NN - 1);                                        \
    if ((lv >> 11) == q) {                                          \
      csrL[(int)qoq[lv & 2047] + (int)rk[E]] =                      \
          (unsigned short)((U) & (NN - 1));                         \
    }                                                               \
    int lu = (U) & (NN - 1);                                        \
    if ((lu >> 11) == q) {                                          \
      csrL[(int)qoq[lu & 2047] + (int)rk[(E) + NPAIR]] =            \
          (unsigned short)((V) & (NN - 1));                         \
    }                                                               \
  }
  for (int e0 = tid; e0 + 3072 < NPAIR; e0 += 4096) {
    int u0 = NTL(up + e0);
    int u1 = NTL(up + e0 + 1024);
    int u2 = NTL(up + e0 + 2048);
    int u3 = NTL(up + e0 + 3072);
    int v0 = NTL(vp + e0);
    int v1 = NTL(vp + e0 + 1024);
    int v2 = NTL(vp + e0 + 2048);
    int v3 = NTL(vp + e0 + 3072);
    SCAT(u0, v0, e0) SCAT(u1, v1, e0 + 1024) SCAT(u2, v2, e0 + 2048) SCAT(u3, v3, e0 + 3072)
  }
#undef SCAT
  __syncthreads();

  // pull: register accumulation, 4-edge ILP; dis on the fly from u8 degree
  const size_t base = (size_t)r * BN + (size_t)b * NN;
  const float4* x4 = (const float4*)x + base;
#pragma unroll
  for (int k = 0; k < 2; ++k) {
    int idx = tid + k * 1024;            // index within quarter
    int n = q * 2048 + idx;              // local node id
    int o = (int)qoq[idx];
    int c = (int)degL[n];
    float sx = 0.f, sy = 0.f, sz = 0.f, sw = 0.f;
    int j = 0;
    for (; j + 3 < c; j += 4) {
      int s0 = csrL[o + j], s1 = csrL[o + j + 1], s2 = csrL[o + j + 2], s3 = csrL[o + j + 3];
      float d0 = rsqrtf((float)degL[s0] + 1.0f);
      float d1 = rsqrtf((float)degL[s1] + 1.0f);
      float d2 = rsqrtf((float)degL[s2] + 1.0f);
      float d3 = rsqrtf((float)degL[s3] + 1.0f);
      float4 a0 = x4[s0], a1 = x4[s1], a2 = x4[s2], a3 = x4[s3];
      sx += a0.x * d0 + a1.x * d1 + a2.x * d2 + a3.x * d3;
      sy += a0.y * d0 + a1.y * d1 + a2.y * d2 + a3.y * d3;
      sz += a0.z * d0 + a1.z * d1 + a2.z * d2 + a3.z * d3;
      sw += a0.w * d0 + a1.w * d1 + a2.w * d2 + a3.w * d3;
    }
    for (; j < c; ++j) {
      int s0 = csrL[o + j];
      float d0 = rsqrtf((float)degL[s0] + 1.0f);
      float4 a0 = x4[s0];
      sx += a0.x * d0; sy += a0.y * d0; sz += a0.z * d0; sw += a0.w * d0;
    }
    float dd = rsqrtf((float)c + 1.0f);
    ((float4*)P4)[base + n] = make_float4(sx * dd, sy * dd, sz * dd, sw * dd);
  }
}

// ---------------- per-(ROI,patient): combine + graph-LN + score + radix-select topK + pools ----------------
__global__ __launch_bounds__(1024)
void roi_kernel(const float* __restrict__ x,
                const float* __restrict__ gcn_w,
                const float* __restrict__ gcn_b,
                const float* __restrict__ ln_w,
                const float* __restrict__ ln_b,
                const float* __restrict__ topk_w,
                const float* __restrict__ cen,
                const unsigned short* __restrict__ qoffg,
                const int* __restrict__ qtotg,
                const float* __restrict__ P4,
                float* __restrict__ feats) {
  const int r = blockIdx.x / BB;
  const int b = blockIdx.x % BB;
  const int rb = blockIdx.x;
  const int tid = threadIdx.x;

  __shared__ unsigned short qos[8192];  // 16 KB
  __shared__ int qt4[4];
  __shared__ double dred[1024];
  __shared__ int tscan[1024];
  __shared__ int hist[256];
  __shared__ float chanSum[8];
  __shared__ float fvSum[8];
  __shared__ int cntGt;
  __shared__ int selb, kleft;

  for (int i = tid; i < 8192; i += 1024) qos[i] = qoffg[(size_t)rb * 8192 + i];
  if (tid < 4) qt4[tid] = qtotg[rb * 4 + tid];
  if (tid < 8) { chanSum[tid] = 0.f; fvSum[tid] = 0.f; }
  if (tid == 0) cntGt = 0;

  float w[32], bg[8], lw[8], lb[8], wt[8];
#pragma unroll
  for (int i = 0; i < 32; ++i) w[i] = gcn_w[r * 32 + i];
  float wn2 = 0.f;
#pragma unroll
  for (int c = 0; c < 8; ++c) {
    bg[c] = gcn_b[r * 8 + c];
    lw[c] = ln_w[r * 8 + c];
    lb[c] = ln_b[r * 8 + c];
    wt[c] = topk_w[r * 8 + c];
    wn2 += wt[c] * wt[c];
  }
  const float invn = 1.0f / sqrtf(wn2);
  __syncthreads();

  const size_t base = (size_t)r * BN + (size_t)b * NN;
  const float4* x4 = (const float4*)x + base;
  const float4* p4 = (const float4*)P4 + base;

  // v4[n] = P4[n] + x[n]/(deg+1) ; hrelu[c] = relu(v4 @ W[:,c] + bg[c])
#define V4(n, out)                                                  \
  {                                                                 \
    int idx_ = (n) & 2047, qq_ = (n) >> 11;                         \
    int nxt_ = (idx_ < 2047) ? (int)qos[(n) + 1] : qt4[qq_];        \
    float invd = 1.0f / ((float)(nxt_ - (int)qos[n]) + 1.0f);       \
    float4 pv = p4[n];                                              \
    float4 xv = x4[n];                                              \
    out.x = pv.x + xv.x * invd;                                     \
    out.y = pv.y + xv.y * invd;                                     \
    out.z = pv.z + xv.z * invd;                                     \
    out.w = pv.w + xv.w * invd;                                     \
  }
#define HREL(v4v, c) fmaxf(v4v.x * w[c] + v4v.y * w[8 + c] + v4v.z * w[16 + c] + v4v.w * w[24 + c] + bg[c], 0.0f)

  // Pass A: fp64 LN stats over hrelu
  double s1 = 0.0, s2 = 0.0;
#pragma unroll
  for (int i = 0; i < 8; ++i) {
    int n = tid * 8 + i;
    float4 vv; V4(n, vv)
#pragma unroll
    for (int c = 0; c < 8; ++c) {
      float v = HREL(vv, c);
      s1 += v;
      s2 += (double)v * v;
    }
  }
  dred[tid] = s1;
  __syncthreads();
  for (int off = 512; off > 0; off >>= 1) {
    if (tid < off) dred[tid] += dred[tid + off];
    __syncthreads();
  }
  double tot1 = dred[0];
  __syncthreads();
  dred[tid] = s2;
  __syncthreads();
  for (int off = 512; off > 0; off >>= 1) {
    if (tid < off) dred[tid] += dred[tid + off];
    __syncthreads();
  }
  double tot2 = dred[0];
  const double M = (double)NN * HH;
  double mu = tot1 / M;
  double var = tot2 / M - mu * mu;
  float muf = (float)mu;
  float rstd = (float)(1.0 / sqrt(var + 1e-5));

  // Pass B: hn, per-channel sums, scores
  float ch[8] = {0, 0, 0, 0, 0, 0, 0, 0};
  float sv[8];
  unsigned fl[8];
#pragma unroll
  for (int i = 0; i < 8; ++i) {
    int n = tid * 8 + i;
    float4 vv; V4(n, vv)
    float pre = 0.f;
#pragma unroll
    for (int c = 0; c < 8; ++c) {
      float v = HREL(vv, c);
      float hn = (v - muf) * rstd * lw[c] + lb[c];
      ch[c] += hn;
      pre += hn * wt[c];
    }
    float s = tanhf(pre * invn);
    sv[i] = s;
    unsigned u = __float_as_uint(s);
    fl[i] = (u & 0x80000000u) ? ~u : (u | 0x80000000u);  // monotonic flip
  }
#pragma unroll
  for (int c = 0; c < 8; ++c) atomicAdd(&chanSum[c], ch[c]);

  // Radix-select the K-th largest (exact), 4 passes of 8 bits
  unsigned prefix = 0;
  int kneed = KK;
  for (int shift = 24; shift >= 0; shift -= 8) {
    __syncthreads();
    if (tid < 256) hist[tid] = 0;
    __syncthreads();
#pragma unroll
    for (int i = 0; i < 8; ++i) {
      bool m = (shift == 24) || ((fl[i] >> (shift + 8)) == prefix);
      if (m) atomicAdd(&hist[(fl[i] >> shift) & 255], 1);
    }
    __syncthreads();
    if (tid == 0) {
      int kn = kneed, bsel = 0;
      for (int bb2 = 255; bb2 >= 0; --bb2) {
        int c = hist[bb2];
        if (kn - c <= 0) { bsel = bb2; break; }
        kn -= c;
      }
      selb = bsel; kleft = kn;
    }
    __syncthreads();
    prefix = (prefix << 8) | (unsigned)selb;
    kneed = kleft;
  }
  float tau = (prefix & 0x80000000u) ? __uint_as_float(prefix & 0x7fffffffu)
                                     : __uint_as_float(~prefix);

  // tie-break lowest-index-first (matches lax.top_k's selected set)
  int cg = 0, ct = 0;
#pragma unroll
  for (int i = 0; i < 8; ++i) {
    if (sv[i] > tau) cg++;
    else if (sv[i] == tau) ct++;
  }
  atomicAdd(&cntGt, cg);
  tscan[tid] = ct;
  __syncthreads();
  if (tid == 0) {
    int run = 0;
    for (int t = 0; t < 1024; ++t) { int tmp = tscan[t]; tscan[t] = run; run += tmp; }
  }
  __syncthreads();
  int quota = KK - cntGt;
  int rank = tscan[tid];
  float fva[8] = {0, 0, 0, 0, 0, 0, 0, 0};
#pragma unroll
  for (int i = 0; i < 8; ++i) {
    bool inc = sv[i] > tau;
    if (!inc && sv[i] == tau) { inc = (rank < quota); rank++; }
    if (inc) {
      int n = tid * 8 + i;
      float4 vv; V4(n, vv)
#pragma unroll
      for (int c = 0; c < 8; ++c) {
        float v = HREL(vv, c);
        float hn = (v - muf) * rstd * lw[c] + lb[c];
        fva[c] += hn * sv[i];
      }
    }
  }
#undef V4
#undef HREL
#pragma unroll
  for (int c = 0; c < 8; ++c) atomicAdd(&fvSum[c], fva[c]);
  __syncthreads();

  size_t fo = (size_t)(r * BB + b) * 19;
  if (tid < 8) {
    feats[fo + tid] = chanSum[tid] / (float)NN;        // res
    feats[fo + 8 + tid] = fvSum[tid] / (float)KK;      // fv
  }
  if (tid >= 16 && tid < 19) {
    feats[fo + tid] = cen[(size_t)(r * BB + b) * 3 + (tid - 16)];
  }
}

// ---------------- super graph: GAT1 -> LN -> GAT2 -> LN -> pool -> linear ----------------
__global__ __launch_bounds__(256)
void super_kernel(const float* __restrict__ feats,
                  const float* __restrict__ W1, const float* __restrict__ as1,
                  const float* __restrict__ ad1, const float* __restrict__ b1,
                  const float* __restrict__ lnw1, const float* __restrict__ lnb1,
                  const float* __restrict__ W2, const float* __restrict__ as2,
                  const float* __restrict__ ad2, const float* __restrict__ b2,
                  const float* __restrict__ lnw2, const float* __restrict__ lnb2,
                  const float* __restrict__ linw, const float* __restrict__ linb,
                  float* __restrict__ out) {
  __shared__ float sx[NSUP * 19];
  __shared__ float h1[NSUP * 64];
  __shared__ float x1[NSUP * 64];
  __shared__ float es1[NSUP * 4], ed1[NSUP * 4];
  __shared__ float h2[NSUP * 16], x2[NSUP * 16];
  __shared__ float es2[NSUP], ed2[NSUP];
  __shared__ float stat[16];
  const int tid = threadIdx.x;

  for (int i = tid; i < NSUP * 19; i += 256) {
    int n = i / 19, c = i % 19;
    int bb = n / RR, rr = n % RR;
    sx[i] = feats[(size_t)(rr * BB + bb) * 19 + c];
  }
  __syncthreads();
  for (int p = tid; p < NSUP * 64; p += 256) {
    int n = p / 64, j = p % 64;
    float acc = 0.f;
    for (int k2 = 0; k2 < 19; ++k2) acc += sx[n * 19 + k2] * W1[k2 * 64 + j];
    h1[p] = acc;
  }
  __syncthreads();
  for (int p = tid; p < NSUP * 4; p += 256) {
    int n = p / 4, hd = p % 4;
    float a = 0.f, d2 = 0.f;
    for (int o = 0; o < 16; ++o) {
      float hv = h1[n * 64 + hd * 16 + o];
      a += hv * as1[hd * 16 + o];
      d2 += hv * ad1[hd * 16 + o];
    }
    es1[p] = a; ed1[p] = d2;
  }
  __syncthreads();
  for (int p = tid; p < NSUP * 64; p += 256) {
    int n = p / 64, j = p % 64, hd = j / 16;
    int rr = n % RR;
    float o;
    if (rr == 0) {
      o = h1[p];
    } else {
      int hub = n - rr;
      float eh = es1[hub * 4 + hd] + ed1[n * 4 + hd];
      float esf = es1[n * 4 + hd] + ed1[n * 4 + hd];
      eh = eh > 0.f ? eh : 0.2f * eh;
      esf = esf > 0.f ? esf : 0.2f * esf;
      float m = fmaxf(eh, esf);
      float wh = expf(eh - m), ws2 = expf(esf - m);
      o = (wh * h1[hub * 64 + j] + ws2 * h1[n * 64 + j]) / (wh + ws2);
    }
    float v = o + b1[j];
    x1[p] = v > 0.f ? v : expm1f(v);   // elu
  }
  __syncthreads();
  if (tid < BB) {
    double m = 0.0, v2 = 0.0;
    for (int q = 0; q < RR * 64; ++q) {
      float val = x1[tid * RR * 64 + q];
      m += val; v2 += (double)val * val;
    }
    m /= (RR * 64.0); v2 = v2 / (RR * 64.0) - m * m;
    stat[tid] = (float)m;
    stat[8 + tid] = (float)(1.0 / sqrt(v2 + 1e-5));
  }
  __syncthreads();
  for (int p = tid; p < NSUP * 64; p += 256) {
    int n = p / 64, j = p % 64, bb = n / RR;
    x1[p] = (x1[p] - stat[bb]) * stat[8 + bb] * lnw1[j] + lnb1[j];
  }
  __syncthreads();
  for (int p = tid; p < NSUP * 16; p += 256) {
    int n = p / 16, o = p % 16;
    float acc = 0.f;
    for (int j = 0; j < 64; ++j) acc += x1[n * 64 + j] * W2[j * 16 + o];
    h2[p] = acc;
  }
  __syncthreads();
  for (int n = tid; n < NSUP; n += 256) {
    float a = 0.f, d2 = 0.f;
    for (int o = 0; o < 16; ++o) {
      float hv = h2[n * 16 + o];
      a += hv * as2[o];
      d2 += hv * ad2[o];
    }
    es2[n] = a; ed2[n] = d2;
  }
  __syncthreads();
  for (int p = tid; p < NSUP * 16; p += 256) {
    int n = p / 16, o = p % 16;
    int rr = n % RR;
    float ov;
    if (rr == 0) ov = h2[p];
    else {
      int hub = n - rr;
      float eh = es2[hub] + ed2[n];
      float esf = es2[n] + ed2[n];
      eh = eh > 0.f ? eh : 0.2f * eh;
      esf = esf > 0.f ? esf : 0.2f * esf;
      float m = fmaxf(eh, esf);
      float wh = expf(eh - m), ws2 = expf(esf - m);
      ov = (wh * h2[hub * 16 + o] + ws2 * h2[p]) / (wh + ws2);
    }
    float v = ov + b2[o];
    x2[p] = v > 0.f ? v : expm1f(v);
  }
  __syncthreads();
  if (tid < BB) {
    double m = 0.0, v2 = 0.0;
    for (int q = 0; q < RR * 16; ++q) {
      float val = x2[tid * RR * 16 + q];
      m += val; v2 += (double)val * val;
    }
    m /= (RR * 16.0); v2 = v2 / (RR * 16.0) - m * m;
    stat[tid] = (float)m;
    stat[8 + tid] = (float)(1.0 / sqrt(v2 + 1e-5));
  }
  __syncthreads();
  for (int p = tid; p < NSUP * 16; p += 256) {
    int n = p / 16, o = p % 16, bb = n / RR;
    x2[p] = (x2[p] - stat[bb]) * stat[8 + bb] * lnw2[o] + lnb2[o];
  }
  __syncthreads();
  if (tid < BB * 2) {
    int bb = tid / 2, t = tid % 2;
    float acc = linb[t];
    for (int o = 0; o < 16; ++o) {
      float pm = 0.f;
      for (int rr = 0; rr < RR; ++rr) pm += x2[(bb * RR + rr) * 16 + o];
      pm /= (float)RR;
      acc += pm * linw[o * 2 + t];
    }
    out[bb * 2 + t] = acc;
  }
}

extern "C" void kernel_launch(void* const* d_in, const int* in_sizes, int n_in,
                              void* d_out, int out_size, void* d_ws, size_t ws_size,
                              hipStream_t stream) {
  const float* roi_x = (const float*)d_in[0];
  const int* ei = (const int*)d_in[1];
  const float* cen = (const float*)d_in[2];
  const float* gcn_w = (const float*)d_in[3];
  const float* gcn_b = (const float*)d_in[4];
  const float* ln_w = (const float*)d_in[5];
  const float* ln_b = (const float*)d_in[6];
  const float* topk_w = (const float*)d_in[7];
  const float* gat1_w = (const float*)d_in[8];
  const float* as1 = (const float*)d_in[9];
  const float* ad1 = (const float*)d_in[10];
  const float* b1 = (const float*)d_in[11];
  const float* lnw1 = (const float*)d_in[12];
  const float* lnb1 = (const float*)d_in[13];
  const float* W2 = (const float*)d_in[14];
  const float* as2 = (const float*)d_in[15];
  const float* ad2 = (const float*)d_in[16];
  const float* b2 = (const float*)d_in[17];
  const float* lnw2 = (const float*)d_in[18];
  const float* lnb2 = (const float*)d_in[19];
  const float* linw = (const float*)d_in[20];
  const float* linb = (const float*)d_in[21];
  float* out = (float*)d_out;

  // ws layout (bytes): P4 f32 [R*BN*4] =10.49MB | qoff u16 [80*8192] =1.31MB | qtot i32 [320]
  //  | feats f32 [1520] | rank u8 [80*EPB] =10.49MB   total ~22.3MB (no global CSR anymore)
  char* wsb = (char*)d_ws;
  float* P4 = (float*)wsb;
  unsigned short* qoff = (unsigned short*)(wsb + (size_t)RR * BN * 4 * 4);
  int* qtot = (int*)((char*)qoff + (size_t)80 * 8192 * 2);
  float* feats = (float*)((char*)qtot + 320 * 4);
  unsigned char* rankg = (unsigned char*)((char*)feats + (size_t)RR * BB * 19 * 4);

  count_kernel<<<320, 1024, 0, stream>>>(ei, rankg, qoff, qtot);
  scatpull_kernel<<<320, 1024, 0, stream>>>(ei, roi_x, rankg, qoff, qtot, P4);
  roi_kernel<<<RR * BB, 1024, 0, stream>>>(roi_x, gcn_w, gcn_b, ln_w, ln_b,
                                           topk_w, cen, qoff, qtot, P4, feats);
  super_kernel<<<1, 256, 0, stream>>>(feats, gat1_w, as1, ad1, b1, lnw1, lnb1,
                                      W2, as2, ad2, b2, lnw2, lnb2, linw, linb, out);
}

// Round 12
// 300.785 us; speedup vs baseline: 2.1232x; 1.0249x over previous
//
#include <hip/hip_runtime.h>
#include <hip/hip_bf16.h>
#include <math.h>

// Problem constants (match reference)
#define RR 10
#define BB 8
#define NN 8192
#define HH 8
#define BN 65536            // BB*NN nodes per ROI
#define EE (1u << 20)       // directed edges per ROI = 2*B*EPAIR
#define EPB (EE / BB)       // 131072 directed edges per (ROI,patient), contiguous
#define NPAIR (EPB / 2)     // 65536 undirected pairs per (r,b)
#define KK 4096             // TopKPooling keeps K of NN
#define NSUP 80             // B*R super nodes
#define CSRL 34560          // LDS CSR slots per quarter: mean 32768, sigma~157 -> +11 sigma

#define NTL(p) __builtin_nontemporal_load(p)

// ---------------- k1: count in-degree per (r,b,dst-quarter); persist per-edge rank (uchar) ----------------
__global__ __launch_bounds__(1024)
void count_kernel(const int* __restrict__ ei, unsigned char* __restrict__ rankg,
                  unsigned short* __restrict__ qoffg, int* __restrict__ qtotg) {
  const int bid = blockIdx.x;
  const int rb = bid % 80;
  const int q = bid / 80;                 // dst quarter 0..3
  const int r = rb / BB;
  const int b = rb % BB;
  const int tid = threadIdx.x;

  __shared__ int scnt[2048];
  __shared__ int ps[1024];
  scnt[tid] = 0; scnt[tid + 1024] = 0;
  __syncthreads();

  const int* up = ei + (size_t)r * 2u * EE + (size_t)b * EPB;        // pair u side
  const int* vp = ei + (size_t)r * 2u * EE + EE + (size_t)b * EPB;   // pair v side
  unsigned char* rk = rankg + (size_t)rb * EPB;

#define CNT(U, V, E)                                                \
  {                                                                 \
    int lv = (V) & (NN - 1);                                        \
    if ((lv >> 11) == q) {                                          \
      int t0 = atomicAdd(&scnt[lv & 2047], 1);                      \
      rk[E] = (unsigned char)t0;                                    \
    }                                                               \
    int lu = (U) & (NN - 1);                                        \
    if ((lu >> 11) == q) {                                          \
      int t1 = atomicAdd(&scnt[lu & 2047], 1);                      \
      rk[(E) + NPAIR] = (unsigned char)t1;                          \
    }                                                               \
  }
  for (int e0 = tid; e0 + 3072 < NPAIR; e0 += 4096) {
    int u0 = NTL(up + e0);
    int u1 = NTL(up + e0 + 1024);
    int u2 = NTL(up + e0 + 2048);
    int u3 = NTL(up + e0 + 3072);
    int v0 = NTL(vp + e0);
    int v1 = NTL(vp + e0 + 1024);
    int v2 = NTL(vp + e0 + 2048);
    int v3 = NTL(vp + e0 + 3072);
    CNT(u0, v0, e0) CNT(u1, v1, e0 + 1024) CNT(u2, v2, e0 + 2048) CNT(u3, v3, e0 + 3072)
  }
#undef CNT
  __syncthreads();

  // exclusive scan over this quarter's 2048 counts (thread owns 2t, 2t+1)
  int a = scnt[2 * tid], b2 = scnt[2 * tid + 1];
  ps[tid] = a + b2;
  __syncthreads();
  for (int s2 = 1; s2 < 1024; s2 <<= 1) {
    int v = 0;
    if (tid >= s2) v = ps[tid - s2];
    __syncthreads();
    ps[tid] += v;
    __syncthreads();
  }
  int ebase = ps[tid] - a - b2;
  size_t ob = (size_t)rb * 8192 + (size_t)q * 2048;
  qoffg[ob + 2 * tid] = (unsigned short)ebase;
  qoffg[ob + 2 * tid + 1] = (unsigned short)(ebase + a);
  if (tid == 1023) qtotg[rb * 4 + q] = ps[1023];
}

// ---------------- k2: LDS-CSR scatter + pull + FUSED GCN epilogue ----------------
// Produces hrelu (hbuf, 8ch), score key t = sum_c hrelu_c*lw_c*wt_c, and LN partials.
__global__ __launch_bounds__(1024)
void scatfuse_kernel(const int* __restrict__ ei, const float* __restrict__ x,
                     const unsigned char* __restrict__ rankg,
                     const unsigned short* __restrict__ qoffg, const int* __restrict__ qtotg,
                     const float* __restrict__ gcn_w, const float* __restrict__ gcn_b,
                     const float* __restrict__ ln_w, const float* __restrict__ topk_w,
                     float* __restrict__ hbuf, float* __restrict__ tg,
                     double* __restrict__ partsS, float* __restrict__ partsC) {
  const int bid = blockIdx.x;
  const int rb = bid % 80;
  const int q = bid / 80;
  const int r = rb / BB;
  const int b = rb % BB;
  const int tid = threadIdx.x;

  __shared__ unsigned short qoq[2048];                 // 4 KB
  __shared__ unsigned char degL[NN];                   // 8 KB
  __shared__ __align__(16) unsigned short csrL[CSRL];  // 67.5 KB (scratch-reused post-pull)
  __shared__ int qt4[4];                               // total ~79.5 KB -> 2 blk/CU

  if (tid < 4) qt4[tid] = qtotg[rb * 4 + tid];
  __syncthreads();
  const unsigned short* qof = qoffg + (size_t)rb * 8192;
  for (int i = tid; i < NN; i += 1024) {
    int idx = i & 2047, qq = i >> 11;
    int cur = qof[i];
    int nxt = (idx < 2047) ? (int)qof[i + 1] : qt4[qq];
    degL[i] = (unsigned char)(nxt - cur);
    if (qq == q) qoq[idx] = (unsigned short)cur;
  }
  __syncthreads();

  const int* up = ei + (size_t)r * 2u * EE + (size_t)b * EPB;
  const int* vp = ei + (size_t)r * 2u * EE + EE + (size_t)b * EPB;
  const unsigned char* rk = rankg + (size_t)rb * EPB;

#define SCAT(U, V, E)                                               \
  {                                                                 \
    int lv = (V) & (NN - 1);                                        \
    if ((lv >> 11) == q) {                                          \
      csrL[(int)qoq[lv & 2047] + (int)rk[E]] =                      \
          (unsigned short)((U) & (NN - 1));                         \
    }                                                               \
    int lu = (U) & (NN - 1);                                        \
    if ((lu >> 11) == q) {                                          \
      csrL[(int)qoq[lu & 2047] + (int)rk[(E) + NPAIR]] =            \
          (unsigned short)((V) & (NN - 1));                         \
    }                                                               \
  }
  for (int e0 = tid; e0 + 3072 < NPAIR; e0 += 4096) {
    int u0 = NTL(up + e0);
    int u1 = NTL(up + e0 + 1024);
    int u2 = NTL(up + e0 + 2048);
    int u3 = NTL(up + e0 + 3072);
    int v0 = NTL(vp + e0);
    int v1 = NTL(vp + e0 + 1024);
    int v2 = NTL(vp + e0 + 2048);
    int v3 = NTL(vp + e0 + 3072);
    SCAT(u0, v0, e0) SCAT(u1, v1, e0 + 1024) SCAT(u2, v2, e0 + 2048) SCAT(u3, v3, e0 + 3072)
  }
#undef SCAT
  __syncthreads();

  // per-r constants (wave-uniform -> scalar loads)
  const float* wp = gcn_w + r * 32;
  const float* bgp = gcn_b + r * 8;
  float lwwt[8];
#pragma unroll
  for (int c = 0; c < 8; ++c) lwwt[c] = ln_w[r * 8 + c] * topk_w[r * 8 + c];

  const size_t base = (size_t)r * BN + (size_t)b * NN;
  const float4* x4 = (const float4*)x + base;
  float4* hb4 = (float4*)hbuf + (size_t)rb * NN * 2;
  float* trow = tg + (size_t)rb * NN;

  double s1 = 0.0, s2 = 0.0;
  float ch[8] = {0, 0, 0, 0, 0, 0, 0, 0};

#pragma unroll
  for (int k = 0; k < 2; ++k) {
    int idx = tid + k * 1024;
    int n = q * 2048 + idx;
    int o = (int)qoq[idx];
    int c = (int)degL[n];
    float sx = 0.f, sy = 0.f, sz = 0.f, sw = 0.f;
    int j = 0;
    for (; j + 3 < c; j += 4) {
      int n0 = csrL[o + j], n1 = csrL[o + j + 1], n2 = csrL[o + j + 2], n3 = csrL[o + j + 3];
      float d0 = rsqrtf((float)degL[n0] + 1.0f);
      float d1 = rsqrtf((float)degL[n1] + 1.0f);
      float d2 = rsqrtf((float)degL[n2] + 1.0f);
      float d3 = rsqrtf((float)degL[n3] + 1.0f);
      float4 a0 = x4[n0], a1 = x4[n1], a2 = x4[n2], a3 = x4[n3];
      sx += a0.x * d0 + a1.x * d1 + a2.x * d2 + a3.x * d3;
      sy += a0.y * d0 + a1.y * d1 + a2.y * d2 + a3.y * d3;
      sz += a0.z * d0 + a1.z * d1 + a2.z * d2 + a3.z * d3;
      sw += a0.w * d0 + a1.w * d1 + a2.w * d2 + a3.w * d3;
    }
    for (; j < c; ++j) {
      int n0 = csrL[o + j];
      float d0 = rsqrtf((float)degL[n0] + 1.0f);
      float4 a0 = x4[n0];
      sx += a0.x * d0; sy += a0.y * d0; sz += a0.z * d0; sw += a0.w * d0;
    }
    float dd = rsqrtf((float)c + 1.0f);
    float invd = 1.0f / ((float)c + 1.0f);
    float4 xv = x4[n];
    float v0 = sx * dd + xv.x * invd;
    float v1 = sy * dd + xv.y * invd;
    float v2 = sz * dd + xv.z * invd;
    float v3 = sw * dd + xv.w * invd;
    float4 hlo, hhi;
    float t = 0.f;
#pragma unroll
    for (int cc = 0; cc < 8; ++cc) {
      float h = fmaxf(v0 * wp[cc] + v1 * wp[8 + cc] + v2 * wp[16 + cc] + v3 * wp[24 + cc] + bgp[cc], 0.0f);
      ((float*)&hlo)[cc < 4 ? cc : 0] = (cc < 4) ? h : ((float*)&hlo)[0];  // placeholder avoided below
      s1 += h;
      s2 += (double)h * h;
      ch[cc] += h;
      t += h * lwwt[cc];
      if (cc == 0) hlo.x = h; else if (cc == 1) hlo.y = h; else if (cc == 2) hlo.z = h;
      else if (cc == 3) hlo.w = h; else if (cc == 4) hhi.x = h; else if (cc == 5) hhi.y = h;
      else if (cc == 6) hhi.z = h; else hhi.w = h;
    }
    hb4[(size_t)n * 2] = hlo;
    hb4[(size_t)n * 2 + 1] = hhi;
    trow[n] = t;
  }

  // block-reduce partials; reuse csrL as scratch (done with CSR)
  __syncthreads();
  double* wredS = (double*)csrL;              // 16 x 2 doubles @ 0
  float* wredC = (float*)(csrL + 512);        // 16 x 8 floats @ +1024B
  int lane = tid & 63, wid = tid >> 6;
#pragma unroll
  for (int off = 32; off > 0; off >>= 1) {
    s1 += __shfl_down(s1, off);
    s2 += __shfl_down(s2, off);
#pragma unroll
    for (int cc = 0; cc < 8; ++cc) ch[cc] += __shfl_down(ch[cc], off);
  }
  if (lane == 0) {
    wredS[wid * 2] = s1;
    wredS[wid * 2 + 1] = s2;
#pragma unroll
    for (int cc = 0; cc < 8; ++cc) wredC[wid * 8 + cc] = ch[cc];
  }
  __syncthreads();
  if (tid == 0) {
    double a = 0.0, b3 = 0.0;
    for (int w2 = 0; w2 < 16; ++w2) { a += wredS[w2 * 2]; b3 += wredS[w2 * 2 + 1]; }
    partsS[bid * 2] = a;
    partsS[bid * 2 + 1] = b3;
  }
  if (tid < 8) {
    float sc = 0.f;
    for (int w2 = 0; w2 < 16; ++w2) sc += wredC[w2 * 8 + tid];
    partsC[bid * 8 + tid] = sc;
  }
}

// ---------------- k3: per-(r,b) stats combine + score + radix-select topK + pools ----------------
__global__ __launch_bounds__(1024)
void roiB_kernel(const float* __restrict__ tg, const float* __restrict__ hbuf,
                 const double* __restrict__ partsS, const float* __restrict__ partsC,
                 const float* __restrict__ ln_w, const float* __restrict__ ln_b,
                 const float* __restrict__ topk_w, const float* __restrict__ cen,
                 float* __restrict__ feats) {
  const int rb = blockIdx.x;
  const int r = rb / BB;
  const int tid = threadIdx.x;

  __shared__ int hist[256];
  __shared__ int ips[1024];
  __shared__ float chS[8];
  __shared__ float fvSum[8];
  __shared__ int cntGt;
  __shared__ int selb, kleft;
  __shared__ float sstat[2];

  float lw[8], lb[8], wt[8];
  float wn2 = 0.f, L1 = 0.f, B1 = 0.f;
#pragma unroll
  for (int c = 0; c < 8; ++c) {
    lw[c] = ln_w[r * 8 + c];
    lb[c] = ln_b[r * 8 + c];
    wt[c] = topk_w[r * 8 + c];
    wn2 += wt[c] * wt[c];
    L1 += lw[c] * wt[c];
    B1 += lb[c] * wt[c];
  }
  const float invn = 1.0f / sqrtf(wn2);

  if (tid == 0) {
    double s1 = 0.0, s2 = 0.0;
    for (int q = 0; q < 4; ++q) {
      s1 += partsS[(q * 80 + rb) * 2];
      s2 += partsS[(q * 80 + rb) * 2 + 1];
    }
    const double M = (double)NN * HH;
    double mu = s1 / M;
    double var = s2 / M - mu * mu;
    sstat[0] = (float)mu;
    sstat[1] = (float)(1.0 / sqrt(var + 1e-5));
    cntGt = 0;
  }
  if (tid < 8) {
    float sc = 0.f;
    for (int q = 0; q < 4; ++q) sc += partsC[(q * 80 + rb) * 8 + tid];
    chS[tid] = sc;
    fvSum[tid] = 0.f;
  }
  __syncthreads();
  const float muf = sstat[0];
  const float rstd = sstat[1];
  const float C0 = B1 - rstd * muf * L1;   // pre = rstd*t + C0

  const float* trow = tg + (size_t)rb * NN;
  float sv[8];
  unsigned fl[8];
#pragma unroll
  for (int i = 0; i < 8; ++i) {
    int n = tid * 8 + i;
    float s = tanhf((rstd * trow[n] + C0) * invn);
    sv[i] = s;
    unsigned u = __float_as_uint(s);
    fl[i] = (u & 0x80000000u) ? ~u : (u | 0x80000000u);
  }

  // Radix-select the K-th largest (exact), 4 passes of 8 bits
  unsigned prefix = 0;
  int kneed = KK;
  for (int shift = 24; shift >= 0; shift -= 8) {
    __syncthreads();
    if (tid < 256) hist[tid] = 0;
    __syncthreads();
#pragma unroll
    for (int i = 0; i < 8; ++i) {
      bool m = (shift == 24) || ((fl[i] >> (shift + 8)) == prefix);
      if (m) atomicAdd(&hist[(fl[i] >> shift) & 255], 1);
    }
    __syncthreads();
    if (tid == 0) {
      int kn = kneed, bsel = 0;
      for (int bb2 = 255; bb2 >= 0; --bb2) {
        int c = hist[bb2];
        if (kn - c <= 0) { bsel = bb2; break; }
        kn -= c;
      }
      selb = bsel; kleft = kn;
    }
    __syncthreads();
    prefix = (prefix << 8) | (unsigned)selb;
    kneed = kleft;
  }
  float tau = (prefix & 0x80000000u) ? __uint_as_float(prefix & 0x7fffffffu)
                                     : __uint_as_float(~prefix);

  // tie-break lowest-index-first (parallel exclusive scan)
  int cg = 0, ct = 0;
#pragma unroll
  for (int i = 0; i < 8; ++i) {
    if (sv[i] > tau) cg++;
    else if (sv[i] == tau) ct++;
  }
  atomicAdd(&cntGt, cg);
  ips[tid] = ct;
  __syncthreads();
  for (int s2 = 1; s2 < 1024; s2 <<= 1) {
    int v = 0;
    if (tid >= s2) v = ips[tid - s2];
    __syncthreads();
    ips[tid] += v;
    __syncthreads();
  }
  int rank = ips[tid] - ct;                // exclusive prefix of tie counts
  int quota = KK - cntGt;

  const float4* hb4 = (const float4*)hbuf + (size_t)rb * NN * 2;
  float fva[8] = {0, 0, 0, 0, 0, 0, 0, 0};
#pragma unroll
  for (int i = 0; i < 8; ++i) {
    bool inc = sv[i] > tau;
    if (!inc && sv[i] == tau) { inc = (rank < quota); rank++; }
    if (inc) {
      int n = tid * 8 + i;
      float4 hlo = hb4[(size_t)n * 2];
      float4 hhi = hb4[(size_t)n * 2 + 1];
      float hh[8] = {hlo.x, hlo.y, hlo.z, hlo.w, hhi.x, hhi.y, hhi.z, hhi.w};
#pragma unroll
      for (int c = 0; c < 8; ++c) {
        float hn = (hh[c] - muf) * rstd * lw[c] + lb[c];
        fva[c] += hn * sv[i];
      }
    }
  }
#pragma unroll
  for (int c = 0; c < 8; ++c) atomicAdd(&fvSum[c], fva[c]);
  __syncthreads();

  size_t fo = (size_t)rb * 19;
  if (tid < 8) {
    // res_c = mean_n hn_c = ((SC_c - N*mu)*rstd*lw_c + N*lb_c)/N
    feats[fo + tid] = ((chS[tid] - (float)NN * muf) * rstd * lw[tid]) / (float)NN + lb[tid];
    feats[fo + 8 + tid] = fvSum[tid] / (float)KK;
  }
  if (tid >= 16 && tid < 19) {
    feats[fo + tid] = cen[(size_t)rb * 3 + (tid - 16)];
  }
}

// ---------------- super graph: GAT1 -> LN -> GAT2 -> LN -> pool -> linear ----------------
__global__ __launch_bounds__(256)
void super_kernel(const float* __restrict__ feats,
                  const float* __restrict__ W1, const float* __restrict__ as1,
                  const float* __restrict__ ad1, const float* __restrict__ b1,
                  const float* __restrict__ lnw1, const float* __restrict__ lnb1,
                  const float* __restrict__ W2, const float* __restrict__ as2,
                  const float* __restrict__ ad2, const float* __restrict__ b2,
                  const float* __restrict__ lnw2, const float* __restrict__ lnb2,
                  const float* __restrict__ linw, const float* __restrict__ linb,
                  float* __restrict__ out) {
  __shared__ float sx[NSUP * 19];
  __shared__ float h1[NSUP * 64];
  __shared__ float x1[NSUP * 64];
  __shared__ float es1[NSUP * 4], ed1[NSUP * 4];
  __shared__ float h2[NSUP * 16], x2[NSUP * 16];
  __shared__ float es2[NSUP], ed2[NSUP];
  __shared__ float stat[16];
  const int tid = threadIdx.x;

  for (int i = tid; i < NSUP * 19; i += 256) {
    int n = i / 19, c = i % 19;
    int bb = n / RR, rr = n % RR;
    sx[i] = feats[(size_t)(rr * BB + bb) * 19 + c];
  }
  __syncthreads();
  for (int p = tid; p < NSUP * 64; p += 256) {
    int n = p / 64, j = p % 64;
    float acc = 0.f;
    for (int k2 = 0; k2 < 19; ++k2) acc += sx[n * 19 + k2] * W1[k2 * 64 + j];
    h1[p] = acc;
  }
  __syncthreads();
  for (int p = tid; p < NSUP * 4; p += 256) {
    int n = p / 4, hd = p % 4;
    float a = 0.f, d2 = 0.f;
    for (int o = 0; o < 16; ++o) {
      float hv = h1[n * 64 + hd * 16 + o];
      a += hv * as1[hd * 16 + o];
      d2 += hv * ad1[hd * 16 + o];
    }
    es1[p] = a; ed1[p] = d2;
  }
  __syncthreads();
  for (int p = tid; p < NSUP * 64; p += 256) {
    int n = p / 64, j = p % 64, hd = j / 16;
    int rr = n % RR;
    float o;
    if (rr == 0) {
      o = h1[p];
    } else {
      int hub = n - rr;
      float eh = es1[hub * 4 + hd] + ed1[n * 4 + hd];
      float esf = es1[n * 4 + hd] + ed1[n * 4 + hd];
      eh = eh > 0.f ? eh : 0.2f * eh;
      esf = esf > 0.f ? esf : 0.2f * esf;
      float m = fmaxf(eh, esf);
      float wh = expf(eh - m), ws2 = expf(esf - m);
      o = (wh * h1[hub * 64 + j] + ws2 * h1[n * 64 + j]) / (wh + ws2);
    }
    float v = o + b1[j];
    x1[p] = v > 0.f ? v : expm1f(v);   // elu
  }
  __syncthreads();
  if (tid < BB) {
    double m = 0.0, v2 = 0.0;
    for (int q = 0; q < RR * 64; ++q) {
      float val = x1[tid * RR * 64 + q];
      m += val; v2 += (double)val * val;
    }
    m /= (RR * 64.0); v2 = v2 / (RR * 64.0) - m * m;
    stat[tid] = (float)m;
    stat[8 + tid] = (float)(1.0 / sqrt(v2 + 1e-5));
  }
  __syncthreads();
  for (int p = tid; p < NSUP * 64; p += 256) {
    int n = p / 64, j = p % 64, bb = n / RR;
    x1[p] = (x1[p] - stat[bb]) * stat[8 + bb] * lnw1[j] + lnb1[j];
  }
  __syncthreads();
  for (int p = tid; p < NSUP * 16; p += 256) {
    int n = p / 16, o = p % 16;
    float acc = 0.f;
    for (int j = 0; j < 64; ++j) acc += x1[n * 64 + j] * W2[j * 16 + o];
    h2[p] = acc;
  }
  __syncthreads();
  for (int n = tid; n < NSUP; n += 256) {
    float a = 0.f, d2 = 0.f;
    for (int o = 0; o < 16; ++o) {
      float hv = h2[n * 16 + o];
      a += hv * as2[o];
      d2 += hv * ad2[o];
    }
    es2[n] = a; ed2[n] = d2;
  }
  __syncthreads();
  for (int p = tid; p < NSUP * 16; p += 256) {
    int n = p / 16, o = p % 16;
    int rr = n % RR;
    float ov;
    if (rr == 0) ov = h2[p];
    else {
      int hub = n - rr;
      float eh = es2[hub] + ed2[n];
      float esf = es2[n] + ed2[n];
      eh = eh > 0.f ? eh : 0.2f * eh;
      esf = esf > 0.f ? esf : 0.2f * esf;
      float m = fmaxf(eh, esf);
      float wh = expf(eh - m), ws2 = expf(esf - m);
      ov = (wh * h2[hub * 16 + o] + ws2 * h2[p]) / (wh + ws2);
    }
    float v = ov + b2[o];
    x2[p] = v > 0.f ? v : expm1f(v);
  }
  __syncthreads();
  if (tid < BB) {
    double m = 0.0, v2 = 0.0;
    for (int q = 0; q < RR * 16; ++q) {
      float val = x2[tid * RR * 16 + q];
      m += val; v2 += (double)val * val;
    }
    m /= (RR * 16.0); v2 = v2 / (RR * 16.0) - m * m;
    stat[tid] = (float)m;
    stat[8 + tid] = (float)(1.0 / sqrt(v2 + 1e-5));
  }
  __syncthreads();
  for (int p = tid; p < NSUP * 16; p += 256) {
    int n = p / 16, o = p % 16, bb = n / RR;
    x2[p] = (x2[p] - stat[bb]) * stat[8 + bb] * lnw2[o] + lnb2[o];
  }
  __syncthreads();
  if (tid < BB * 2) {
    int bb = tid / 2, t = tid % 2;
    float acc = linb[t];
    for (int o = 0; o < 16; ++o) {
      float pm = 0.f;
      for (int rr = 0; rr < RR; ++rr) pm += x2[(bb * RR + rr) * 16 + o];
      pm /= (float)RR;
      acc += pm * linw[o * 2 + t];
    }
    out[bb * 2 + t] = acc;
  }
}

extern "C" void kernel_launch(void* const* d_in, const int* in_sizes, int n_in,
                              void* d_out, int out_size, void* d_ws, size_t ws_size,
                              hipStream_t stream) {
  const float* roi_x = (const float*)d_in[0];
  const int* ei = (const int*)d_in[1];
  const float* cen = (const float*)d_in[2];
  const float* gcn_w = (const float*)d_in[3];
  const float* gcn_b = (const float*)d_in[4];
  const float* ln_w = (const float*)d_in[5];
  const float* ln_b = (const float*)d_in[6];
  const float* topk_w = (const float*)d_in[7];
  const float* gat1_w = (const float*)d_in[8];
  const float* as1 = (const float*)d_in[9];
  const float* ad1 = (const float*)d_in[10];
  const float* b1 = (const float*)d_in[11];
  const float* lnw1 = (const float*)d_in[12];
  const float* lnb1 = (const float*)d_in[13];
  const float* W2 = (const float*)d_in[14];
  const float* as2 = (const float*)d_in[15];
  const float* ad2 = (const float*)d_in[16];
  const float* b2 = (const float*)d_in[17];
  const float* lnw2 = (const float*)d_in[18];
  const float* lnb2 = (const float*)d_in[19];
  const float* linw = (const float*)d_in[20];
  const float* linb = (const float*)d_in[21];
  float* out = (float*)d_out;

  // ws (bytes): hbuf f32[80*8192*8]=20.97MB | tg f32[80*8192]=2.62MB | partsS f64[640]=5KB
  //  | partsC f32[2560]=10KB | qoff u16[80*8192]=1.31MB | qtot i32[320] | feats f32[1520]
  //  | rank u8[80*EPB]=10.49MB   total ~35.4MB
  char* wsb = (char*)d_ws;
  float* hbuf = (float*)wsb;
  float* tg = (float*)(wsb + (size_t)80 * NN * 8 * 4);
  double* partsS = (double*)((char*)tg + (size_t)80 * NN * 4);
  float* partsC = (float*)((char*)partsS + 640 * 8);
  unsigned short* qoff = (unsigned short*)((char*)partsC + 2560 * 4);
  int* qtot = (int*)((char*)qoff + (size_t)80 * 8192 * 2);
  float* feats = (float*)((char*)qtot + 320 * 4);
  unsigned char* rankg = (unsigned char*)((char*)feats + (size_t)RR * BB * 19 * 4);

  count_kernel<<<320, 1024, 0, stream>>>(ei, rankg, qoff, qtot);
  scatfuse_kernel<<<320, 1024, 0, stream>>>(ei, roi_x, rankg, qoff, qtot,
                                            gcn_w, gcn_b, ln_w, topk_w,
                                            hbuf, tg, partsS, partsC);
  roiB_kernel<<<80, 1024, 0, stream>>>(tg, hbuf, partsS, partsC,
                                       ln_w, ln_b, topk_w, cen, feats);
  super_kernel<<<1, 256, 0, stream>>>(feats, gat1_w, as1, ad1, b1, lnw1, lnb1,
                                      W2, as2, ad2, b2, lnw2, lnb2, linw, linb, out);
}

// Round 13
// 296.748 us; speedup vs baseline: 2.1521x; 1.0136x over previous
//
#include <hip/hip_runtime.h>
#include <hip/hip_bf16.h>
#include <math.h>

// Problem constants (match reference)
#define RR 10
#define BB 8
#define NN 8192
#define HH 8
#define BN 65536            // BB*NN nodes per ROI
#define EE (1u << 20)       // directed edges per ROI = 2*B*EPAIR
#define EPB (EE / BB)       // 131072 directed edges per (ROI,patient), contiguous
#define NPAIR (EPB / 2)     // 65536 undirected pairs per (r,b)
#define KK 4096             // TopKPooling keeps K of NN
#define NSUP 80             // B*R super nodes
#define CSRL8 17408         // LDS CSR slots per EIGHTH: mean 16384, sigma~120 -> +8.5 sigma

#define NTL(p) __builtin_nontemporal_load(p)

// ---------------- k1: count in-degree per (r,b,dst-quarter); persist per-edge rank (uchar) ----------------
__global__ __launch_bounds__(1024)
void count_kernel(const int* __restrict__ ei, unsigned char* __restrict__ rankg,
                  unsigned short* __restrict__ qoffg, int* __restrict__ qtotg) {
  const int bid = blockIdx.x;
  const int rb = bid % 80;
  const int q = bid / 80;                 // dst quarter 0..3
  const int r = rb / BB;
  const int b = rb % BB;
  const int tid = threadIdx.x;

  __shared__ int scnt[2048];
  __shared__ int ps[1024];
  scnt[tid] = 0; scnt[tid + 1024] = 0;
  __syncthreads();

  const int* up = ei + (size_t)r * 2u * EE + (size_t)b * EPB;        // pair u side
  const int* vp = ei + (size_t)r * 2u * EE + EE + (size_t)b * EPB;   // pair v side
  unsigned char* rk = rankg + (size_t)rb * EPB;

#define CNT(U, V, E)                                                \
  {                                                                 \
    int lv = (V) & (NN - 1);                                        \
    if ((lv >> 11) == q) {                                          \
      int t0 = atomicAdd(&scnt[lv & 2047], 1);                      \
      rk[E] = (unsigned char)t0;                                    \
    }                                                               \
    int lu = (U) & (NN - 1);                                        \
    if ((lu >> 11) == q) {                                          \
      int t1 = atomicAdd(&scnt[lu & 2047], 1);                      \
      rk[(E) + NPAIR] = (unsigned char)t1;                          \
    }                                                               \
  }
  for (int e0 = tid; e0 + 3072 < NPAIR; e0 += 4096) {
    int u0 = NTL(up + e0);
    int u1 = NTL(up + e0 + 1024);
    int u2 = NTL(up + e0 + 2048);
    int u3 = NTL(up + e0 + 3072);
    int v0 = NTL(vp + e0);
    int v1 = NTL(vp + e0 + 1024);
    int v2 = NTL(vp + e0 + 2048);
    int v3 = NTL(vp + e0 + 3072);
    CNT(u0, v0, e0) CNT(u1, v1, e0 + 1024) CNT(u2, v2, e0 + 2048) CNT(u3, v3, e0 + 3072)
  }
#undef CNT
  __syncthreads();

  // exclusive scan over this quarter's 2048 counts (thread owns 2t, 2t+1)
  int a = scnt[2 * tid], b2 = scnt[2 * tid + 1];
  ps[tid] = a + b2;
  __syncthreads();
  for (int s2 = 1; s2 < 1024; s2 <<= 1) {
    int v = 0;
    if (tid >= s2) v = ps[tid - s2];
    __syncthreads();
    ps[tid] += v;
    __syncthreads();
  }
  int ebase = ps[tid] - a - b2;
  size_t ob = (size_t)rb * 8192 + (size_t)q * 2048;
  qoffg[ob + 2 * tid] = (unsigned short)ebase;
  qoffg[ob + 2 * tid + 1] = (unsigned short)(ebase + a);
  if (tid == 1023) qtotg[rb * 4 + q] = ps[1023];
}

// ---------------- k2: per-(rb, node-EIGHTH) LDS-CSR scatter + pull + fused GCN epilogue ----------------
// Eighths (vs quarters) shrink csrL 69->34.8KB => 2 blocks/CU (full 32-wave occupancy).
// rank is node-local => unchanged; eighth-local offsets derived from quarter-local qoff.
__global__ __launch_bounds__(1024)
void scatfuse_kernel(const int* __restrict__ ei, const float* __restrict__ x,
                     const unsigned char* __restrict__ rankg,
                     const unsigned short* __restrict__ qoffg, const int* __restrict__ qtotg,
                     const float* __restrict__ gcn_w, const float* __restrict__ gcn_b,
                     const float* __restrict__ ln_w, const float* __restrict__ topk_w,
                     float* __restrict__ hbuf, float* __restrict__ tg,
                     double* __restrict__ partsS, float* __restrict__ partsC) {
  const int bid = blockIdx.x;
  const int rb = bid % 80;
  const int p = bid / 80;                  // node eighth 0..7
  const int q = p >> 1;                    // parent quarter
  const int half = p & 1;
  const int r = rb / BB;
  const int b = rb % BB;
  const int tid = threadIdx.x;

  __shared__ unsigned short qo8[1024];                 // eighth-local offsets (2 KB)
  __shared__ unsigned char degL[NN];                   // all nodes' degree (8 KB)
  __shared__ __align__(16) unsigned short csrL[CSRL8]; // 34.8 KB  -> total ~45 KB, 2 blk/CU
  __shared__ int qt4[4];

  if (tid < 4) qt4[tid] = qtotg[rb * 4 + tid];
  __syncthreads();
  const unsigned short* qof = qoffg + (size_t)rb * 8192;
  for (int i = tid; i < NN; i += 1024) {
    int idx = i & 2047, qq = i >> 11;
    int cur = qof[i];
    int nxt = (idx < 2047) ? (int)qof[i + 1] : qt4[qq];
    degL[i] = (unsigned char)(nxt - cur);
  }
  // eighth base within quarter-local offset space
  const int base8 = half ? (int)qof[q * 2048 + 1024] : 0;
  if (tid < 1024) {
    int n = p * 1024 + tid;
    qo8[tid] = (unsigned short)((int)qof[n] - base8);
  }
  __syncthreads();

  const int* up = ei + (size_t)r * 2u * EE + (size_t)b * EPB;
  const int* vp = ei + (size_t)r * 2u * EE + EE + (size_t)b * EPB;
  const unsigned char* rk = rankg + (size_t)rb * EPB;

  // scatter: plain LDS stores, race-free by precomputed rank; filter by eighth
#define SCAT(U, V, E)                                               \
  {                                                                 \
    int lv = (V) & (NN - 1);                                        \
    if ((lv >> 10) == p) {                                          \
      csrL[(int)qo8[lv & 1023] + (int)rk[E]] =                      \
          (unsigned short)((U) & (NN - 1));                         \
    }                                                               \
    int lu = (U) & (NN - 1);                                        \
    if ((lu >> 10) == p) {                                          \
      csrL[(int)qo8[lu & 1023] + (int)rk[(E) + NPAIR]] =            \
          (unsigned short)((V) & (NN - 1));                         \
    }                                                               \
  }
  for (int e0 = tid; e0 + 3072 < NPAIR; e0 += 4096) {
    int u0 = NTL(up + e0);
    int u1 = NTL(up + e0 + 1024);
    int u2 = NTL(up + e0 + 2048);
    int u3 = NTL(up + e0 + 3072);
    int v0 = NTL(vp + e0);
    int v1 = NTL(vp + e0 + 1024);
    int v2 = NTL(vp + e0 + 2048);
    int v3 = NTL(vp + e0 + 3072);
    SCAT(u0, v0, e0) SCAT(u1, v1, e0 + 1024) SCAT(u2, v2, e0 + 2048) SCAT(u3, v3, e0 + 3072)
  }
#undef SCAT
  __syncthreads();

  // per-r constants (wave-uniform -> scalar loads)
  const float* wp = gcn_w + r * 32;
  const float* bgp = gcn_b + r * 8;
  float lwwt[8];
#pragma unroll
  for (int c = 0; c < 8; ++c) lwwt[c] = ln_w[r * 8 + c] * topk_w[r * 8 + c];

  const size_t base = (size_t)r * BN + (size_t)b * NN;
  const float4* x4 = (const float4*)x + base;
  float4* hb4 = (float4*)hbuf + (size_t)rb * NN * 2;
  float* trow = tg + (size_t)rb * NN;

  double s1 = 0.0, s2 = 0.0;
  float ch[8] = {0, 0, 0, 0, 0, 0, 0, 0};

  {
    int n = p * 1024 + tid;               // one node per thread
    int o = (int)qo8[tid];
    int c = (int)degL[n];
    float sx = 0.f, sy = 0.f, sz = 0.f, sw = 0.f;
    int j = 0;
    for (; j + 3 < c; j += 4) {
      int n0 = csrL[o + j], n1 = csrL[o + j + 1], n2 = csrL[o + j + 2], n3 = csrL[o + j + 3];
      float d0 = rsqrtf((float)degL[n0] + 1.0f);
      float d1 = rsqrtf((float)degL[n1] + 1.0f);
      float d2 = rsqrtf((float)degL[n2] + 1.0f);
      float d3 = rsqrtf((float)degL[n3] + 1.0f);
      float4 a0 = x4[n0], a1 = x4[n1], a2 = x4[n2], a3 = x4[n3];
      sx += a0.x * d0 + a1.x * d1 + a2.x * d2 + a3.x * d3;
      sy += a0.y * d0 + a1.y * d1 + a2.y * d2 + a3.y * d3;
      sz += a0.z * d0 + a1.z * d1 + a2.z * d2 + a3.z * d3;
      sw += a0.w * d0 + a1.w * d1 + a2.w * d2 + a3.w * d3;
    }
    for (; j < c; ++j) {
      int n0 = csrL[o + j];
      float d0 = rsqrtf((float)degL[n0] + 1.0f);
      float4 a0 = x4[n0];
      sx += a0.x * d0; sy += a0.y * d0; sz += a0.z * d0; sw += a0.w * d0;
    }
    float dd = rsqrtf((float)c + 1.0f);
    float invd = 1.0f / ((float)c + 1.0f);
    float4 xv = x4[n];
    float v0 = sx * dd + xv.x * invd;
    float v1 = sy * dd + xv.y * invd;
    float v2 = sz * dd + xv.z * invd;
    float v3 = sw * dd + xv.w * invd;
    float hh[8];
    float t = 0.f;
#pragma unroll
    for (int cc = 0; cc < 8; ++cc) {
      float h = fmaxf(v0 * wp[cc] + v1 * wp[8 + cc] + v2 * wp[16 + cc] + v3 * wp[24 + cc] + bgp[cc], 0.0f);
      hh[cc] = h;
      s1 += h;
      s2 += (double)h * h;
      ch[cc] += h;
      t += h * lwwt[cc];
    }
    hb4[(size_t)n * 2] = make_float4(hh[0], hh[1], hh[2], hh[3]);
    hb4[(size_t)n * 2 + 1] = make_float4(hh[4], hh[5], hh[6], hh[7]);
    trow[n] = t;
  }

  // block-reduce partials; reuse csrL as scratch (done with CSR)
  __syncthreads();
  double* wredS = (double*)csrL;              // 16 x 2 doubles @ 0
  float* wredC = (float*)(csrL + 512);        // 16 x 8 floats @ +1024B
  int lane = tid & 63, wid = tid >> 6;
#pragma unroll
  for (int off = 32; off > 0; off >>= 1) {
    s1 += __shfl_down(s1, off);
    s2 += __shfl_down(s2, off);
#pragma unroll
    for (int cc = 0; cc < 8; ++cc) ch[cc] += __shfl_down(ch[cc], off);
  }
  if (lane == 0) {
    wredS[wid * 2] = s1;
    wredS[wid * 2 + 1] = s2;
#pragma unroll
    for (int cc = 0; cc < 8; ++cc) wredC[wid * 8 + cc] = ch[cc];
  }
  __syncthreads();
  if (tid == 0) {
    double a = 0.0, b3 = 0.0;
    for (int w2 = 0; w2 < 16; ++w2) { a += wredS[w2 * 2]; b3 += wredS[w2 * 2 + 1]; }
    partsS[bid * 2] = a;
    partsS[bid * 2 + 1] = b3;
  }
  if (tid < 8) {
    float sc = 0.f;
    for (int w2 = 0; w2 < 16; ++w2) sc += wredC[w2 * 8 + tid];
    partsC[bid * 8 + tid] = sc;
  }
}

// ---------------- k3: per-(r,b) stats combine + score + radix-select topK + pools ----------------
__global__ __launch_bounds__(1024)
void roiB_kernel(const float* __restrict__ tg, const float* __restrict__ hbuf,
                 const double* __restrict__ partsS, const float* __restrict__ partsC,
                 const float* __restrict__ ln_w, const float* __restrict__ ln_b,
                 const float* __restrict__ topk_w, const float* __restrict__ cen,
                 float* __restrict__ feats) {
  const int rb = blockIdx.x;
  const int r = rb / BB;
  const int tid = threadIdx.x;

  __shared__ int hist[256];
  __shared__ int ips[1024];
  __shared__ float chS[8];
  __shared__ float fvSum[8];
  __shared__ int cntGt;
  __shared__ int selb, kleft;
  __shared__ float sstat[2];

  float lw[8], lb[8], wt[8];
  float wn2 = 0.f, L1 = 0.f, B1 = 0.f;
#pragma unroll
  for (int c = 0; c < 8; ++c) {
    lw[c] = ln_w[r * 8 + c];
    lb[c] = ln_b[r * 8 + c];
    wt[c] = topk_w[r * 8 + c];
    wn2 += wt[c] * wt[c];
    L1 += lw[c] * wt[c];
    B1 += lb[c] * wt[c];
  }
  const float invn = 1.0f / sqrtf(wn2);

  if (tid == 0) {
    double s1 = 0.0, s2 = 0.0;
    for (int p = 0; p < 8; ++p) {
      s1 += partsS[(p * 80 + rb) * 2];
      s2 += partsS[(p * 80 + rb) * 2 + 1];
    }
    const double M = (double)NN * HH;
    double mu = s1 / M;
    double var = s2 / M - mu * mu;
    sstat[0] = (float)mu;
    sstat[1] = (float)(1.0 / sqrt(var + 1e-5));
    cntGt = 0;
  }
  if (tid < 8) {
    float sc = 0.f;
    for (int p = 0; p < 8; ++p) sc += partsC[(p * 80 + rb) * 8 + tid];
    chS[tid] = sc;
    fvSum[tid] = 0.f;
  }
  __syncthreads();
  const float muf = sstat[0];
  const float rstd = sstat[1];
  const float C0 = B1 - rstd * muf * L1;   // pre = rstd*t + C0

  const float* trow = tg + (size_t)rb * NN;
  float sv[8];
  unsigned fl[8];
#pragma unroll
  for (int i = 0; i < 8; ++i) {
    int n = tid * 8 + i;
    float s = tanhf((rstd * trow[n] + C0) * invn);
    sv[i] = s;
    unsigned u = __float_as_uint(s);
    fl[i] = (u & 0x80000000u) ? ~u : (u | 0x80000000u);
  }

  // Radix-select the K-th largest (exact), 4 passes of 8 bits
  unsigned prefix = 0;
  int kneed = KK;
  for (int shift = 24; shift >= 0; shift -= 8) {
    __syncthreads();
    if (tid < 256) hist[tid] = 0;
    __syncthreads();
#pragma unroll
    for (int i = 0; i < 8; ++i) {
      bool m = (shift == 24) || ((fl[i] >> (shift + 8)) == prefix);
      if (m) atomicAdd(&hist[(fl[i] >> shift) & 255], 1);
    }
    __syncthreads();
    if (tid == 0) {
      int kn = kneed, bsel = 0;
      for (int bb2 = 255; bb2 >= 0; --bb2) {
        int c = hist[bb2];
        if (kn - c <= 0) { bsel = bb2; break; }
        kn -= c;
      }
      selb = bsel; kleft = kn;
    }
    __syncthreads();
    prefix = (prefix << 8) | (unsigned)selb;
    kneed = kleft;
  }
  float tau = (prefix & 0x80000000u) ? __uint_as_float(prefix & 0x7fffffffu)
                                     : __uint_as_float(~prefix);

  // tie-break lowest-index-first (parallel exclusive scan)
  int cg = 0, ct = 0;
#pragma unroll
  for (int i = 0; i < 8; ++i) {
    if (sv[i] > tau) cg++;
    else if (sv[i] == tau) ct++;
  }
  atomicAdd(&cntGt, cg);
  ips[tid] = ct;
  __syncthreads();
  for (int s2 = 1; s2 < 1024; s2 <<= 1) {
    int v = 0;
    if (tid >= s2) v = ips[tid - s2];
    __syncthreads();
    ips[tid] += v;
    __syncthreads();
  }
  int rank = ips[tid] - ct;                // exclusive prefix of tie counts
  int quota = KK - cntGt;

  const float4* hb4 = (const float4*)hbuf + (size_t)rb * NN * 2;
  float fva[8] = {0, 0, 0, 0, 0, 0, 0, 0};
#pragma unroll
  for (int i = 0; i < 8; ++i) {
    bool inc = sv[i] > tau;
    if (!inc && sv[i] == tau) { inc = (rank < quota); rank++; }
    if (inc) {
      int n = tid * 8 + i;
      float4 hlo = hb4[(size_t)n * 2];
      float4 hhi = hb4[(size_t)n * 2 + 1];
      float hh[8] = {hlo.x, hlo.y, hlo.z, hlo.w, hhi.x, hhi.y, hhi.z, hhi.w};
#pragma unroll
      for (int c = 0; c < 8; ++c) {
        float hn = (hh[c] - muf) * rstd * lw[c] + lb[c];
        fva[c] += hn * sv[i];
      }
    }
  }
#pragma unroll
  for (int c = 0; c < 8; ++c) atomicAdd(&fvSum[c], fva[c]);
  __syncthreads();

  size_t fo = (size_t)rb * 19;
  if (tid < 8) {
    // res_c = mean_n hn_c = ((SC_c - N*mu)*rstd*lw_c)/N + lb_c
    feats[fo + tid] = ((chS[tid] - (float)NN * muf) * rstd * lw[tid]) / (float)NN + lb[tid];
    feats[fo + 8 + tid] = fvSum[tid] / (float)KK;
  }
  if (tid >= 16 && tid < 19) {
    feats[fo + tid] = cen[(size_t)rb * 3 + (tid - 16)];
  }
}

// ---------------- super graph: GAT1 -> LN -> GAT2 -> LN -> pool -> linear ----------------
__global__ __launch_bounds__(256)
void super_kernel(const float* __restrict__ feats,
                  const float* __restrict__ W1, const float* __restrict__ as1,
                  const float* __restrict__ ad1, const float* __restrict__ b1,
                  const float* __restrict__ lnw1, const float* __restrict__ lnb1,
                  const float* __restrict__ W2, const float* __restrict__ as2,
                  const float* __restrict__ ad2, const float* __restrict__ b2,
                  const float* __restrict__ lnw2, const float* __restrict__ lnb2,
                  const float* __restrict__ linw, const float* __restrict__ linb,
                  float* __restrict__ out) {
  __shared__ float sx[NSUP * 19];
  __shared__ float h1[NSUP * 64];
  __shared__ float x1[NSUP * 64];
  __shared__ float es1[NSUP * 4], ed1[NSUP * 4];
  __shared__ float h2[NSUP * 16], x2[NSUP * 16];
  __shared__ float es2[NSUP], ed2[NSUP];
  __shared__ float stat[16];
  const int tid = threadIdx.x;

  for (int i = tid; i < NSUP * 19; i += 256) {
    int n = i / 19, c = i % 19;
    int bb = n / RR, rr = n % RR;
    sx[i] = feats[(size_t)(rr * BB + bb) * 19 + c];
  }
  __syncthreads();
  for (int p = tid; p < NSUP * 64; p += 256) {
    int n = p / 64, j = p % 64;
    float acc = 0.f;
    for (int k2 = 0; k2 < 19; ++k2) acc += sx[n * 19 + k2] * W1[k2 * 64 + j];
    h1[p] = acc;
  }
  __syncthreads();
  for (int p = tid; p < NSUP * 4; p += 256) {
    int n = p / 4, hd = p % 4;
    float a = 0.f, d2 = 0.f;
    for (int o = 0; o < 16; ++o) {
      float hv = h1[n * 64 + hd * 16 + o];
      a += hv * as1[hd * 16 + o];
      d2 += hv * ad1[hd * 16 + o];
    }
    es1[p] = a; ed1[p] = d2;
  }
  __syncthreads();
  for (int p = tid; p < NSUP * 64; p += 256) {
    int n = p / 64, j = p % 64, hd = j / 16;
    int rr = n % RR;
    float o;
    if (rr == 0) {
      o = h1[p];
    } else {
      int hub = n - rr;
      float eh = es1[hub * 4 + hd] + ed1[n * 4 + hd];
      float esf = es1[n * 4 + hd] + ed1[n * 4 + hd];
      eh = eh > 0.f ? eh : 0.2f * eh;
      esf = esf > 0.f ? esf : 0.2f * esf;
      float m = fmaxf(eh, esf);
      float wh = expf(eh - m), ws2 = expf(esf - m);
      o = (wh * h1[hub * 64 + j] + ws2 * h1[n * 64 + j]) / (wh + ws2);
    }
    float v = o + b1[j];
    x1[p] = v > 0.f ? v : expm1f(v);   // elu
  }
  __syncthreads();
  if (tid < BB) {
    double m = 0.0, v2 = 0.0;
    for (int q = 0; q < RR * 64; ++q) {
      float val = x1[tid * RR * 64 + q];
      m += val; v2 += (double)val * val;
    }
    m /= (RR * 64.0); v2 = v2 / (RR * 64.0) - m * m;
    stat[tid] = (float)m;
    stat[8 + tid] = (float)(1.0 / sqrt(v2 + 1e-5));
  }
  __syncthreads();
  for (int p = tid; p < NSUP * 64; p += 256) {
    int n = p / 64, j = p % 64, bb = n / RR;
    x1[p] = (x1[p] - stat[bb]) * stat[8 + bb] * lnw1[j] + lnb1[j];
  }
  __syncthreads();
  for (int p = tid; p < NSUP * 16; p += 256) {
    int n = p / 16, o = p % 16;
    float acc = 0.f;
    for (int j = 0; j < 64; ++j) acc += x1[n * 64 + j] * W2[j * 16 + o];
    h2[p] = acc;
  }
  __syncthreads();
  for (int n = tid; n < NSUP; n += 256) {
    float a = 0.f, d2 = 0.f;
    for (int o = 0; o < 16; ++o) {
      float hv = h2[n * 16 + o];
      a += hv * as2[o];
      d2 += hv * ad2[o];
    }
    es2[n] = a; ed2[n] = d2;
  }
  __syncthreads();
  for (int p = tid; p < NSUP * 16; p += 256) {
    int n = p / 16, o = p % 16;
    int rr = n % RR;
    float ov;
    if (rr == 0) ov = h2[p];
    else {
      int hub = n - rr;
      float eh = es2[hub] + ed2[n];
      float esf = es2[n] + ed2[n];
      eh = eh > 0.f ? eh : 0.2f * eh;
      esf = esf > 0.f ? esf : 0.2f * esf;
      float m = fmaxf(eh, esf);
      float wh = expf(eh - m), ws2 = expf(esf - m);
      ov = (wh * h2[hub * 16 + o] + ws2 * h2[p]) / (wh + ws2);
    }
    float v = ov + b2[o];
    x2[p] = v > 0.f ? v : expm1f(v);
  }
  __syncthreads();
  if (tid < BB) {
    double m = 0.0, v2 = 0.0;
    for (int q = 0; q < RR * 16; ++q) {
      float val = x2[tid * RR * 16 + q];
      m += val; v2 += (double)val * val;
    }
    m /= (RR * 16.0); v2 = v2 / (RR * 16.0) - m * m;
    stat[tid] = (float)m;
    stat[8 + tid] = (float)(1.0 / sqrt(v2 + 1e-5));
  }
  __syncthreads();
  for (int p = tid; p < NSUP * 16; p += 256) {
    int n = p / 16, o = p % 16, bb = n / RR;
    x2[p] = (x2[p] - stat[bb]) * stat[8 + bb] * lnw2[o] + lnb2[o];
  }
  __syncthreads();
  if (tid < BB * 2) {
    int bb = tid / 2, t = tid % 2;
    float acc = linb[t];
    for (int o = 0; o < 16; ++o) {
      float pm = 0.f;
      for (int rr = 0; rr < RR; ++rr) pm += x2[(bb * RR + rr) * 16 + o];
      pm /= (float)RR;
      acc += pm * linw[o * 2 + t];
    }
    out[bb * 2 + t] = acc;
  }
}

extern "C" void kernel_launch(void* const* d_in, const int* in_sizes, int n_in,
                              void* d_out, int out_size, void* d_ws, size_t ws_size,
                              hipStream_t stream) {
  const float* roi_x = (const float*)d_in[0];
  const int* ei = (const int*)d_in[1];
  const float* cen = (const float*)d_in[2];
  const float* gcn_w = (const float*)d_in[3];
  const float* gcn_b = (const float*)d_in[4];
  const float* ln_w = (const float*)d_in[5];
  const float* ln_b = (const float*)d_in[6];
  const float* topk_w = (const float*)d_in[7];
  const float* gat1_w = (const float*)d_in[8];
  const float* as1 = (const float*)d_in[9];
  const float* ad1 = (const float*)d_in[10];
  const float* b1 = (const float*)d_in[11];
  const float* lnw1 = (const float*)d_in[12];
  const float* lnb1 = (const float*)d_in[13];
  const float* W2 = (const float*)d_in[14];
  const float* as2 = (const float*)d_in[15];
  const float* ad2 = (const float*)d_in[16];
  const float* b2 = (const float*)d_in[17];
  const float* lnw2 = (const float*)d_in[18];
  const float* lnb2 = (const float*)d_in[19];
  const float* linw = (const float*)d_in[20];
  const float* linb = (const float*)d_in[21];
  float* out = (float*)d_out;

  // ws (bytes): hbuf f32[80*8192*8]=20.97MB | tg f32[80*8192]=2.62MB | partsS f64[1280]=10KB
  //  | partsC f32[5120]=20KB | qoff u16[80*8192]=1.31MB | qtot i32[320] | feats f32[1520]
  //  | rank u8[80*EPB]=10.49MB   total ~35.4MB
  char* wsb = (char*)d_ws;
  float* hbuf = (float*)wsb;
  float* tg = (float*)(wsb + (size_t)80 * NN * 8 * 4);
  double* partsS = (double*)((char*)tg + (size_t)80 * NN * 4);
  float* partsC = (float*)((char*)partsS + 1280 * 8);
  unsigned short* qoff = (unsigned short*)((char*)partsC + 5120 * 4);
  int* qtot = (int*)((char*)qoff + (size_t)80 * 8192 * 2);
  float* feats = (float*)((char*)qtot + 320 * 4);
  unsigned char* rankg = (unsigned char*)((char*)feats + (size_t)RR * BB * 19 * 4);

  count_kernel<<<320, 1024, 0, stream>>>(ei, rankg, qoff, qtot);
  scatfuse_kernel<<<640, 1024, 0, stream>>>(ei, roi_x, rankg, qoff, qtot,
                                            gcn_w, gcn_b, ln_w, topk_w,
                                            hbuf, tg, partsS, partsC);
  roiB_kernel<<<80, 1024, 0, stream>>>(tg, hbuf, partsS, partsC,
                                       ln_w, ln_b, topk_w, cen, feats);
  super_kernel<<<1, 256, 0, stream>>>(feats, gat1_w, as1, ad1, b1, lnw1, lnb1,
                                      W2, as2, ad2, b2, lnw2, lnb2, linw, linb, out);
}

// Round 14
// 251.102 us; speedup vs baseline: 2.5433x; 1.1818x over previous
//
#include <hip/hip_runtime.h>
#include <hip/hip_bf16.h>
#include <math.h>

// Problem constants (match reference)
#define RR 10
#define BB 8
#define NN 8192
#define HH 8
#define BN 65536            // BB*NN nodes per ROI
#define EE (1u << 20)       // directed edges per ROI = 2*B*EPAIR
#define EPB (EE / BB)       // 131072 directed edges per (ROI,patient), contiguous
#define NPAIR (EPB / 2)     // 65536 undirected pairs per (r,b)
#define KK 4096             // TopKPooling keeps K of NN
#define NSUP 80             // B*R super nodes
#define CSRL8 17408         // LDS CSR slots per EIGHTH: mean 16384, sigma~120 -> +8.5 sigma

#define NTL(p) __builtin_nontemporal_load(p)

// ---------------- k1: count in-degree per (r,b,dst-quarter) + rank (uchar) + z = x*dis ----------------
__global__ __launch_bounds__(1024)
void count_kernel(const int* __restrict__ ei, const float* __restrict__ x,
                  unsigned char* __restrict__ rankg,
                  unsigned short* __restrict__ qoffg, int* __restrict__ qtotg,
                  float* __restrict__ zg) {
  const int bid = blockIdx.x;
  const int rb = bid % 80;
  const int q = bid / 80;                 // dst quarter 0..3
  const int r = rb / BB;
  const int b = rb % BB;
  const int tid = threadIdx.x;

  __shared__ int scnt[2048];
  __shared__ int ps[1024];
  scnt[tid] = 0; scnt[tid + 1024] = 0;
  __syncthreads();

  const int* up = ei + (size_t)r * 2u * EE + (size_t)b * EPB;        // pair u side
  const int* vp = ei + (size_t)r * 2u * EE + EE + (size_t)b * EPB;   // pair v side
  unsigned char* rk = rankg + (size_t)rb * EPB;

#define CNT(U, V, E)                                                \
  {                                                                 \
    int lv = (V) & (NN - 1);                                        \
    if ((lv >> 11) == q) {                                          \
      int t0 = atomicAdd(&scnt[lv & 2047], 1);                      \
      rk[E] = (unsigned char)t0;                                    \
    }                                                               \
    int lu = (U) & (NN - 1);                                        \
    if ((lu >> 11) == q) {                                          \
      int t1 = atomicAdd(&scnt[lu & 2047], 1);                      \
      rk[(E) + NPAIR] = (unsigned char)t1;                          \
    }                                                               \
  }
  for (int e0 = tid; e0 + 3072 < NPAIR; e0 += 4096) {
    int u0 = NTL(up + e0);
    int u1 = NTL(up + e0 + 1024);
    int u2 = NTL(up + e0 + 2048);
    int u3 = NTL(up + e0 + 3072);
    int v0 = NTL(vp + e0);
    int v1 = NTL(vp + e0 + 1024);
    int v2 = NTL(vp + e0 + 2048);
    int v3 = NTL(vp + e0 + 3072);
    CNT(u0, v0, e0) CNT(u1, v1, e0 + 1024) CNT(u2, v2, e0 + 2048) CNT(u3, v3, e0 + 3072)
  }
#undef CNT
  __syncthreads();

  // exclusive scan over this quarter's 2048 counts (thread owns 2t, 2t+1)
  int a = scnt[2 * tid], b2 = scnt[2 * tid + 1];
  ps[tid] = a + b2;
  __syncthreads();
  for (int s2 = 1; s2 < 1024; s2 <<= 1) {
    int v = 0;
    if (tid >= s2) v = ps[tid - s2];
    __syncthreads();
    ps[tid] += v;
    __syncthreads();
  }
  int ebase = ps[tid] - a - b2;
  size_t ob = (size_t)rb * 8192 + (size_t)q * 2048;
  qoffg[ob + 2 * tid] = (unsigned short)ebase;
  qoffg[ob + 2 * tid + 1] = (unsigned short)(ebase + a);
  if (tid == 1023) qtotg[rb * 4 + q] = ps[1023];

  // z tail: z[n] = x[n] * rsqrt(deg+1)  (own quarter's 2048 nodes, coalesced)
  const float4* x4 = (const float4*)x + (size_t)r * BN + (size_t)b * NN + (size_t)q * 2048;
  float4* z4 = (float4*)zg + (size_t)rb * NN + (size_t)q * 2048;
  for (int i = tid; i < 2048; i += 1024) {
    float ds = rsqrtf((float)scnt[i] + 1.0f);
    float4 xv = x4[i];
    z4[i] = make_float4(xv.x * ds, xv.y * ds, xv.z * ds, xv.w * ds);
  }
}

// ---------------- k2: per-(rb, eighth) LDS-CSR scatter + z-pull + fused GCN epilogue ----------------
// v4[d] = dis[d] * (sum_{s in N(d)} z[s] + z[d])   [z = x*dis; self-term x*dis^2 = z*dis]
__global__ __launch_bounds__(1024)
void scatfuse_kernel(const int* __restrict__ ei, const float* __restrict__ zg,
                     const unsigned char* __restrict__ rankg,
                     const unsigned short* __restrict__ qoffg, const int* __restrict__ qtotg,
                     const float* __restrict__ gcn_w, const float* __restrict__ gcn_b,
                     const float* __restrict__ ln_w, const float* __restrict__ topk_w,
                     float* __restrict__ v4g, float* __restrict__ tg,
                     double* __restrict__ partsS, float* __restrict__ partsC) {
  const int bid = blockIdx.x;
  const int rb = bid % 80;
  const int p = bid / 80;                  // node eighth 0..7
  const int r = rb / BB;
  const int b = rb % BB;
  const int tid = threadIdx.x;

  __shared__ unsigned short qo8[1025];                 // RAW quarter-local offsets (+end)
  __shared__ __align__(16) unsigned short csrL[CSRL8]; // 34.8 KB  -> total ~37 KB, 2 blk/CU
  __shared__ int qt4[4];

  if (tid < 4) qt4[tid] = qtotg[rb * 4 + tid];
  __syncthreads();
  const unsigned short* qof = qoffg + (size_t)rb * 8192;
  if (tid < 1024) qo8[tid] = qof[p * 1024 + tid];
  if (tid == 0)
    qo8[1024] = (p & 1) ? (unsigned short)qt4[p >> 1] : qof[p * 1024 + 1024];
  __syncthreads();
  const int base8 = (int)qo8[0];           // eighth base in quarter-local space

  const int* up = ei + (size_t)r * 2u * EE + (size_t)b * EPB;
  const int* vp = ei + (size_t)r * 2u * EE + EE + (size_t)b * EPB;
  const unsigned char* rk = rankg + (size_t)rb * EPB;

  // scatter: unconditional batched rank loads; plain LDS stores filtered by eighth
#define SCAT(U, V, RA, RB2)                                         \
  {                                                                 \
    int lv = (V) & (NN - 1);                                        \
    if ((lv >> 10) == p) {                                          \
      csrL[(int)qo8[lv & 1023] - base8 + (int)(RA)] =               \
          (unsigned short)((U) & (NN - 1));                         \
    }                                                               \
    int lu = (U) & (NN - 1);                                        \
    if ((lu >> 10) == p) {                                          \
      csrL[(int)qo8[lu & 1023] - base8 + (int)(RB2)] =              \
          (unsigned short)((V) & (NN - 1));                         \
    }                                                               \
  }
  for (int e0 = tid; e0 + 3072 < NPAIR; e0 += 4096) {
    unsigned char ra0 = NTL(rk + e0);
    unsigned char ra1 = NTL(rk + e0 + 1024);
    unsigned char ra2 = NTL(rk + e0 + 2048);
    unsigned char ra3 = NTL(rk + e0 + 3072);
    unsigned char rb0 = NTL(rk + NPAIR + e0);
    unsigned char rb1 = NTL(rk + NPAIR + e0 + 1024);
    unsigned char rb2 = NTL(rk + NPAIR + e0 + 2048);
    unsigned char rb3 = NTL(rk + NPAIR + e0 + 3072);
    int u0 = NTL(up + e0);
    int u1 = NTL(up + e0 + 1024);
    int u2 = NTL(up + e0 + 2048);
    int u3 = NTL(up + e0 + 3072);
    int v0 = NTL(vp + e0);
    int v1 = NTL(vp + e0 + 1024);
    int v2 = NTL(vp + e0 + 2048);
    int v3 = NTL(vp + e0 + 3072);
    SCAT(u0, v0, ra0, rb0) SCAT(u1, v1, ra1, rb1)
    SCAT(u2, v2, ra2, rb2) SCAT(u3, v3, ra3, rb3)
  }
#undef SCAT
  __syncthreads();

  // per-r constants (wave-uniform -> scalar loads)
  const float* wp = gcn_w + r * 32;
  const float* bgp = gcn_b + r * 8;
  float lwwt[8];
#pragma unroll
  for (int c = 0; c < 8; ++c) lwwt[c] = ln_w[r * 8 + c] * topk_w[r * 8 + c];

  const float4* z4 = (const float4*)zg + (size_t)rb * NN;
  float4* v4o = (float4*)v4g + (size_t)rb * NN;
  float* trow = tg + (size_t)rb * NN;

  double s1 = 0.0, s2 = 0.0;
  float ch[8] = {0, 0, 0, 0, 0, 0, 0, 0};

  {
    int n = p * 1024 + tid;               // one node per thread
    int o = (int)qo8[tid] - base8;
    int c = (int)qo8[tid + 1] - (int)qo8[tid];
    float4 zn = z4[n];                    // own z (coalesced)
    float sx = zn.x, sy = zn.y, sz = zn.z, sw = zn.w;   // self-term seed
    int j = 0;
    for (; j + 3 < c; j += 4) {
      int n0 = csrL[o + j], n1 = csrL[o + j + 1], n2 = csrL[o + j + 2], n3 = csrL[o + j + 3];
      float4 a0 = z4[n0], a1 = z4[n1], a2 = z4[n2], a3 = z4[n3];
      sx += a0.x + a1.x + a2.x + a3.x;
      sy += a0.y + a1.y + a2.y + a3.y;
      sz += a0.z + a1.z + a2.z + a3.z;
      sw += a0.w + a1.w + a2.w + a3.w;
    }
    for (; j < c; ++j) {
      int n0 = csrL[o + j];
      float4 a0 = z4[n0];
      sx += a0.x; sy += a0.y; sz += a0.z; sw += a0.w;
    }
    float dd = rsqrtf((float)c + 1.0f);
    float v0 = sx * dd, v1 = sy * dd, v2 = sz * dd, v3 = sw * dd;
    v4o[n] = make_float4(v0, v1, v2, v3);
    float t = 0.f;
#pragma unroll
    for (int cc = 0; cc < 8; ++cc) {
      float h = fmaxf(v0 * wp[cc] + v1 * wp[8 + cc] + v2 * wp[16 + cc] + v3 * wp[24 + cc] + bgp[cc], 0.0f);
      s1 += h;
      s2 += (double)h * h;
      ch[cc] += h;
      t += h * lwwt[cc];
    }
    trow[n] = t;
  }

  // block-reduce partials; reuse csrL as scratch (done with CSR)
  __syncthreads();
  double* wredS = (double*)csrL;              // 16 x 2 doubles @ 0
  float* wredC = (float*)(csrL + 512);        // 16 x 8 floats @ +1024B
  int lane = tid & 63, wid = tid >> 6;
#pragma unroll
  for (int off = 32; off > 0; off >>= 1) {
    s1 += __shfl_down(s1, off);
    s2 += __shfl_down(s2, off);
#pragma unroll
    for (int cc = 0; cc < 8; ++cc) ch[cc] += __shfl_down(ch[cc], off);
  }
  if (lane == 0) {
    wredS[wid * 2] = s1;
    wredS[wid * 2 + 1] = s2;
#pragma unroll
    for (int cc = 0; cc < 8; ++cc) wredC[wid * 8 + cc] = ch[cc];
  }
  __syncthreads();
  if (tid == 0) {
    double a = 0.0, b3 = 0.0;
    for (int w2 = 0; w2 < 16; ++w2) { a += wredS[w2 * 2]; b3 += wredS[w2 * 2 + 1]; }
    partsS[bid * 2] = a;
    partsS[bid * 2 + 1] = b3;
  }
  if (tid < 8) {
    float sc = 0.f;
    for (int w2 = 0; w2 < 16; ++w2) sc += wredC[w2 * 8 + tid];
    partsC[bid * 8 + tid] = sc;
  }
}

// ---------------- k3: per-(r,b) stats combine + score + radix-select topK + pools ----------------
__global__ __launch_bounds__(1024)
void roiB_kernel(const float* __restrict__ tg, const float* __restrict__ v4g,
                 const double* __restrict__ partsS, const float* __restrict__ partsC,
                 const float* __restrict__ gcn_w, const float* __restrict__ gcn_b,
                 const float* __restrict__ ln_w, const float* __restrict__ ln_b,
                 const float* __restrict__ topk_w, const float* __restrict__ cen,
                 float* __restrict__ feats) {
  const int rb = blockIdx.x;
  const int r = rb / BB;
  const int tid = threadIdx.x;

  __shared__ int hist[256];
  __shared__ int ips[1024];
  __shared__ float chS[8];
  __shared__ float fvSum[8];
  __shared__ int cntGt;
  __shared__ int selb, kleft;
  __shared__ float sstat[2];

  float lw[8], lb[8], wt[8], w[32], bg[8];
  float wn2 = 0.f, L1 = 0.f, B1 = 0.f;
#pragma unroll
  for (int i = 0; i < 32; ++i) w[i] = gcn_w[r * 32 + i];
#pragma unroll
  for (int c = 0; c < 8; ++c) {
    lw[c] = ln_w[r * 8 + c];
    lb[c] = ln_b[r * 8 + c];
    wt[c] = topk_w[r * 8 + c];
    bg[c] = gcn_b[r * 8 + c];
    wn2 += wt[c] * wt[c];
    L1 += lw[c] * wt[c];
    B1 += lb[c] * wt[c];
  }
  const float invn = 1.0f / sqrtf(wn2);

  if (tid == 0) {
    double s1 = 0.0, s2 = 0.0;
    for (int p = 0; p < 8; ++p) {
      s1 += partsS[(p * 80 + rb) * 2];
      s2 += partsS[(p * 80 + rb) * 2 + 1];
    }
    const double M = (double)NN * HH;
    double mu = s1 / M;
    double var = s2 / M - mu * mu;
    sstat[0] = (float)mu;
    sstat[1] = (float)(1.0 / sqrt(var + 1e-5));
    cntGt = 0;
  }
  if (tid < 8) {
    float sc = 0.f;
    for (int p = 0; p < 8; ++p) sc += partsC[(p * 80 + rb) * 8 + tid];
    chS[tid] = sc;
    fvSum[tid] = 0.f;
  }
  __syncthreads();
  const float muf = sstat[0];
  const float rstd = sstat[1];
  const float C0 = B1 - rstd * muf * L1;   // pre = rstd*t + C0

  const float* trow = tg + (size_t)rb * NN;
  float sv[8];
  unsigned fl[8];
#pragma unroll
  for (int i = 0; i < 8; ++i) {
    int n = tid * 8 + i;
    float s = tanhf((rstd * trow[n] + C0) * invn);
    sv[i] = s;
    unsigned u = __float_as_uint(s);
    fl[i] = (u & 0x80000000u) ? ~u : (u | 0x80000000u);
  }

  // Radix-select the K-th largest (exact), 4 passes of 8 bits
  unsigned prefix = 0;
  int kneed = KK;
  for (int shift = 24; shift >= 0; shift -= 8) {
    __syncthreads();
    if (tid < 256) hist[tid] = 0;
    __syncthreads();
#pragma unroll
    for (int i = 0; i < 8; ++i) {
      bool m = (shift == 24) || ((fl[i] >> (shift + 8)) == prefix);
      if (m) atomicAdd(&hist[(fl[i] >> shift) & 255], 1);
    }
    __syncthreads();
    if (tid == 0) {
      int kn = kneed, bsel = 0;
      for (int bb2 = 255; bb2 >= 0; --bb2) {
        int c = hist[bb2];
        if (kn - c <= 0) { bsel = bb2; break; }
        kn -= c;
      }
      selb = bsel; kleft = kn;
    }
    __syncthreads();
    prefix = (prefix << 8) | (unsigned)selb;
    kneed = kleft;
  }
  float tau = (prefix & 0x80000000u) ? __uint_as_float(prefix & 0x7fffffffu)
                                     : __uint_as_float(~prefix);

  // tie-break lowest-index-first (parallel exclusive scan)
  int cg = 0, ct = 0;
#pragma unroll
  for (int i = 0; i < 8; ++i) {
    if (sv[i] > tau) cg++;
    else if (sv[i] == tau) ct++;
  }
  atomicAdd(&cntGt, cg);
  ips[tid] = ct;
  __syncthreads();
  for (int s2 = 1; s2 < 1024; s2 <<= 1) {
    int v = 0;
    if (tid >= s2) v = ips[tid - s2];
    __syncthreads();
    ips[tid] += v;
    __syncthreads();
  }
  int rank = ips[tid] - ct;
  int quota = KK - cntGt;

  const float4* v4r = (const float4*)v4g + (size_t)rb * NN;
  float fva[8] = {0, 0, 0, 0, 0, 0, 0, 0};
#pragma unroll
  for (int i = 0; i < 8; ++i) {
    bool inc = sv[i] > tau;
    if (!inc && sv[i] == tau) { inc = (rank < quota); rank++; }
    if (inc) {
      int n = tid * 8 + i;
      float4 vv = v4r[n];
#pragma unroll
      for (int c = 0; c < 8; ++c) {
        float h = fmaxf(vv.x * w[c] + vv.y * w[8 + c] + vv.z * w[16 + c] + vv.w * w[24 + c] + bg[c], 0.0f);
        float hn = (h - muf) * rstd * lw[c] + lb[c];
        fva[c] += hn * sv[i];
      }
    }
  }
#pragma unroll
  for (int c = 0; c < 8; ++c) atomicAdd(&fvSum[c], fva[c]);
  __syncthreads();

  size_t fo = (size_t)rb * 19;
  if (tid < 8) {
    feats[fo + tid] = ((chS[tid] - (float)NN * muf) * rstd * lw[tid]) / (float)NN + lb[tid];
    feats[fo + 8 + tid] = fvSum[tid] / (float)KK;
  }
  if (tid >= 16 && tid < 19) {
    feats[fo + tid] = cen[(size_t)rb * 3 + (tid - 16)];
  }
}

// ---------------- super graph: GAT1 -> LN -> GAT2 -> LN -> pool -> linear ----------------
__global__ __launch_bounds__(256)
void super_kernel(const float* __restrict__ feats,
                  const float* __restrict__ W1, const float* __restrict__ as1,
                  const float* __restrict__ ad1, const float* __restrict__ b1,
                  const float* __restrict__ lnw1, const float* __restrict__ lnb1,
                  const float* __restrict__ W2, const float* __restrict__ as2,
                  const float* __restrict__ ad2, const float* __restrict__ b2,
                  const float* __restrict__ lnw2, const float* __restrict__ lnb2,
                  const float* __restrict__ linw, const float* __restrict__ linb,
                  float* __restrict__ out) {
  __shared__ float sx[NSUP * 19];
  __shared__ float h1[NSUP * 64];
  __shared__ float x1[NSUP * 64];
  __shared__ float es1[NSUP * 4], ed1[NSUP * 4];
  __shared__ float h2[NSUP * 16], x2[NSUP * 16];
  __shared__ float es2[NSUP], ed2[NSUP];
  __shared__ float stat[16];
  const int tid = threadIdx.x;

  for (int i = tid; i < NSUP * 19; i += 256) {
    int n = i / 19, c = i % 19;
    int bb = n / RR, rr = n % RR;
    sx[i] = feats[(size_t)(rr * BB + bb) * 19 + c];
  }
  __syncthreads();
  for (int p = tid; p < NSUP * 64; p += 256) {
    int n = p / 64, j = p % 64;
    float acc = 0.f;
    for (int k2 = 0; k2 < 19; ++k2) acc += sx[n * 19 + k2] * W1[k2 * 64 + j];
    h1[p] = acc;
  }
  __syncthreads();
  for (int p = tid; p < NSUP * 4; p += 256) {
    int n = p / 4, hd = p % 4;
    float a = 0.f, d2 = 0.f;
    for (int o = 0; o < 16; ++o) {
      float hv = h1[n * 64 + hd * 16 + o];
      a += hv * as1[hd * 16 + o];
      d2 += hv * ad1[hd * 16 + o];
    }
    es1[p] = a; ed1[p] = d2;
  }
  __syncthreads();
  for (int p = tid; p < NSUP * 64; p += 256) {
    int n = p / 64, j = p % 64, hd = j / 16;
    int rr = n % RR;
    float o;
    if (rr == 0) {
      o = h1[p];
    } else {
      int hub = n - rr;
      float eh = es1[hub * 4 + hd] + ed1[n * 4 + hd];
      float esf = es1[n * 4 + hd] + ed1[n * 4 + hd];
      eh = eh > 0.f ? eh : 0.2f * eh;
      esf = esf > 0.f ? esf : 0.2f * esf;
      float m = fmaxf(eh, esf);
      float wh = expf(eh - m), ws2 = expf(esf - m);
      o = (wh * h1[hub * 64 + j] + ws2 * h1[n * 64 + j]) / (wh + ws2);
    }
    float v = o + b1[j];
    x1[p] = v > 0.f ? v : expm1f(v);   // elu
  }
  __syncthreads();
  if (tid < BB) {
    double m = 0.0, v2 = 0.0;
    for (int q = 0; q < RR * 64; ++q) {
      float val = x1[tid * RR * 64 + q];
      m += val; v2 += (double)val * val;
    }
    m /= (RR * 64.0); v2 = v2 / (RR * 64.0) - m * m;
    stat[tid] = (float)m;
    stat[8 + tid] = (float)(1.0 / sqrt(v2 + 1e-5));
  }
  __syncthreads();
  for (int p = tid; p < NSUP * 64; p += 256) {
    int n = p / 64, j = p % 64, bb = n / RR;
    x1[p] = (x1[p] - stat[bb]) * stat[8 + bb] * lnw1[j] + lnb1[j];
  }
  __syncthreads();
  for (int p = tid; p < NSUP * 16; p += 256) {
    int n = p / 16, o = p % 16;
    float acc = 0.f;
    for (int j = 0; j < 64; ++j) acc += x1[n * 64 + j] * W2[j * 16 + o];
    h2[p] = acc;
  }
  __syncthreads();
  for (int n = tid; n < NSUP; n += 256) {
    float a = 0.f, d2 = 0.f;
    for (int o = 0; o < 16; ++o) {
      float hv = h2[n * 16 + o];
      a += hv * as2[o];
      d2 += hv * ad2[o];
    }
    es2[n] = a; ed2[n] = d2;
  }
  __syncthreads();
  for (int p = tid; p < NSUP * 16; p += 256) {
    int n = p / 16, o = p % 16;
    int rr = n % RR;
    float ov;
    if (rr == 0) ov = h2[p];
    else {
      int hub = n - rr;
      float eh = es2[hub] + ed2[n];
      float esf = es2[n] + ed2[n];
      eh = eh > 0.f ? eh : 0.2f * eh;
      esf = esf > 0.f ? esf : 0.2f * esf;
      float m = fmaxf(eh, esf);
      float wh = expf(eh - m), ws2 = expf(esf - m);
      ov = (wh * h2[hub * 16 + o] + ws2 * h2[p]) / (wh + ws2);
    }
    float v = ov + b2[o];
    x2[p] = v > 0.f ? v : expm1f(v);
  }
  __syncthreads();
  if (tid < BB) {
    double m = 0.0, v2 = 0.0;
    for (int q = 0; q < RR * 16; ++q) {
      float val = x2[tid * RR * 16 + q];
      m += val; v2 += (double)val * val;
    }
    m /= (RR * 16.0); v2 = v2 / (RR * 16.0) - m * m;
    stat[tid] = (float)m;
    stat[8 + tid] = (float)(1.0 / sqrt(v2 + 1e-5));
  }
  __syncthreads();
  for (int p = tid; p < NSUP * 16; p += 256) {
    int n = p / 16, o = p % 16, bb = n / RR;
    x2[p] = (x2[p] - stat[bb]) * stat[8 + bb] * lnw2[o] + lnb2[o];
  }
  __syncthreads();
  if (tid < BB * 2) {
    int bb = tid / 2, t = tid % 2;
    float acc = linb[t];
    for (int o = 0; o < 16; ++o) {
      float pm = 0.f;
      for (int rr = 0; rr < RR; ++rr) pm += x2[(bb * RR + rr) * 16 + o];
      pm /= (float)RR;
      acc += pm * linw[o * 2 + t];
    }
    out[bb * 2 + t] = acc;
  }
}

extern "C" void kernel_launch(void* const* d_in, const int* in_sizes, int n_in,
                              void* d_out, int out_size, void* d_ws, size_t ws_size,
                              hipStream_t stream) {
  const float* roi_x = (const float*)d_in[0];
  const int* ei = (const int*)d_in[1];
  const float* cen = (const float*)d_in[2];
  const float* gcn_w = (const float*)d_in[3];
  const float* gcn_b = (const float*)d_in[4];
  const float* ln_w = (const float*)d_in[5];
  const float* ln_b = (const float*)d_in[6];
  const float* topk_w = (const float*)d_in[7];
  const float* gat1_w = (const float*)d_in[8];
  const float* as1 = (const float*)d_in[9];
  const float* ad1 = (const float*)d_in[10];
  const float* b1 = (const float*)d_in[11];
  const float* lnw1 = (const float*)d_in[12];
  const float* lnb1 = (const float*)d_in[13];
  const float* W2 = (const float*)d_in[14];
  const float* as2 = (const float*)d_in[15];
  const float* ad2 = (const float*)d_in[16];
  const float* b2 = (const float*)d_in[17];
  const float* lnw2 = (const float*)d_in[18];
  const float* lnb2 = (const float*)d_in[19];
  const float* linw = (const float*)d_in[20];
  const float* linb = (const float*)d_in[21];
  float* out = (float*)d_out;

  // ws (bytes): v4g f32[80*8192*4]=10.49MB | zg f32[80*8192*4]=10.49MB | tg f32[80*8192]=2.62MB
  //  | partsS f64[1280]=10KB | partsC f32[5120]=20KB | qoff u16[80*8192]=1.31MB | qtot i32[320]
  //  | feats f32[1520] | rank u8[80*EPB]=10.49MB   total ~35.4MB (<=44.57MB proven)
  char* wsb = (char*)d_ws;
  float* v4g = (float*)wsb;
  float* zg = (float*)(wsb + (size_t)80 * NN * 4 * 4);
  float* tg = (float*)((char*)zg + (size_t)80 * NN * 4 * 4);
  double* partsS = (double*)((char*)tg + (size_t)80 * NN * 4);
  float* partsC = (float*)((char*)partsS + 1280 * 8);
  unsigned short* qoff = (unsigned short*)((char*)partsC + 5120 * 4);
  int* qtot = (int*)((char*)qoff + (size_t)80 * 8192 * 2);
  float* feats = (float*)((char*)qtot + 320 * 4);
  unsigned char* rankg = (unsigned char*)((char*)feats + (size_t)RR * BB * 19 * 4);

  count_kernel<<<320, 1024, 0, stream>>>(ei, roi_x, rankg, qoff, qtot, zg);
  scatfuse_kernel<<<640, 1024, 0, stream>>>(ei, zg, rankg, qoff, qtot,
                                            gcn_w, gcn_b, ln_w, topk_w,
                                            v4g, tg, partsS, partsC);
  roiB_kernel<<<80, 1024, 0, stream>>>(tg, v4g, partsS, partsC,
                                       gcn_w, gcn_b, ln_w, ln_b, topk_w, cen, feats);
  super_kernel<<<1, 256, 0, stream>>>(feats, gat1_w, as1, ad1, b1, lnw1, lnb1,
                                      W2, as2, ad2, b2, lnw2, lnb2, linw, linb, out);
}